// Round 1
// baseline (1954.970 us; speedup 1.0000x reference)
//
#include <hip/hip_runtime.h>
#include <math.h>

#define D_MODEL 1024
#define NUM_HEAD 16
#define D_HEAD   64
#define BATCH    4
#define SEQ      2048
#define MTOT     (BATCH*SEQ)   // 8192 rows

// ---------------------------------------------------------------------------
// Kernel 1: fp32 tiled GEMM  Y = X @ W + bias, output scattered to (B,H,S,dh)
// BM=BN=128, BK=16, 256 threads, 8x8 acc per thread.
// ---------------------------------------------------------------------------
#define BM 128
#define BN 128
#define BKT 16
#define LDP (BM + 4)

__global__ __launch_bounds__(256) void qkv_gemm(
    const float* __restrict__ X, const float* __restrict__ W,
    const float* __restrict__ bias, float* __restrict__ Y)
{
    __shared__ float As[BKT][LDP];
    __shared__ float Bs[BKT][LDP];

    const int t  = threadIdx.x;
    const int tx = t & 15;
    const int ty = t >> 4;
    const int m0 = blockIdx.y * BM;
    const int n0 = blockIdx.x * BN;

    float acc[8][8];
#pragma unroll
    for (int i = 0; i < 8; ++i)
#pragma unroll
        for (int j = 0; j < 8; ++j) acc[i][j] = 0.f;

    const int am = t >> 1;          // 0..127  (A row within tile)
    const int ak = (t & 1) * 8;     // 0 or 8  (A k-offset)
    const int bkr = t >> 4;         // 0..15   (B k-row)
    const int bn  = (t & 15) * 4;   // 0..60   (B col offset)

    for (int k0 = 0; k0 < D_MODEL; k0 += BKT) {
        float4 a0 = *(const float4*)&X[(size_t)(m0 + am) * D_MODEL + k0 + ak];
        float4 a1 = *(const float4*)&X[(size_t)(m0 + am) * D_MODEL + k0 + ak + 4];
        float4 b0 = *(const float4*)&W[(size_t)(k0 + bkr) * D_MODEL + n0 + bn];
        float4 b1 = *(const float4*)&W[(size_t)(k0 + bkr) * D_MODEL + n0 + bn + 64];
        __syncthreads();
        As[ak+0][am] = a0.x; As[ak+1][am] = a0.y; As[ak+2][am] = a0.z; As[ak+3][am] = a0.w;
        As[ak+4][am] = a1.x; As[ak+5][am] = a1.y; As[ak+6][am] = a1.z; As[ak+7][am] = a1.w;
        *(float4*)&Bs[bkr][bn]      = b0;
        *(float4*)&Bs[bkr][bn + 64] = b1;
        __syncthreads();
#pragma unroll
        for (int k = 0; k < BKT; ++k) {
            float4 av0 = *(const float4*)&As[k][ty*8];
            float4 av1 = *(const float4*)&As[k][ty*8+4];
            float4 bv0 = *(const float4*)&Bs[k][tx*8];
            float4 bv1 = *(const float4*)&Bs[k][tx*8+4];
            float a[8] = {av0.x,av0.y,av0.z,av0.w,av1.x,av1.y,av1.z,av1.w};
            float b[8] = {bv0.x,bv0.y,bv0.z,bv0.w,bv1.x,bv1.y,bv1.z,bv1.w};
#pragma unroll
            for (int i = 0; i < 8; ++i)
#pragma unroll
                for (int j = 0; j < 8; ++j)
                    acc[i][j] = fmaf(a[i], b[j], acc[i][j]);
        }
    }

    // Epilogue: bias add, scatter into (B, H, S, dh). Each 8-col group lies in
    // exactly one head (64 % 8 == 0), so rows are contiguous float4x2 writes.
    const int gn = n0 + tx*8;
    const int h  = gn >> 6;
    const int dl = gn & 63;
    float bb[8];
#pragma unroll
    for (int j = 0; j < 8; ++j) bb[j] = bias[gn + j];

#pragma unroll
    for (int i = 0; i < 8; ++i) {
        int row  = m0 + ty*8 + i;
        int bidx = row >> 11;          // row / SEQ
        int srow = row & (SEQ - 1);    // row % SEQ
        float* dst = &Y[(((size_t)bidx*NUM_HEAD + h)*SEQ + srow)*D_HEAD + dl];
        float4 w0 = make_float4(acc[i][0]+bb[0], acc[i][1]+bb[1], acc[i][2]+bb[2], acc[i][3]+bb[3]);
        float4 w1 = make_float4(acc[i][4]+bb[4], acc[i][5]+bb[5], acc[i][6]+bb[6], acc[i][7]+bb[7]);
        *(float4*)&dst[0] = w0;
        *(float4*)&dst[4] = w1;
    }
}

// ---------------------------------------------------------------------------
// Kernel 2: causal flash attention, fp32 vector ALU.
// One thread = one query row (q[64], o[64] in regs). KV tiles of 32 in LDS,
// read broadcast (conflict-free). Online softmax with skip-rescale.
// Output written in (B, S, D) layout for the LN kernel.
// ---------------------------------------------------------------------------
#define QB  128
#define KVT 32

__global__ __launch_bounds__(128) void attn_fwd(
    const float* __restrict__ Q, const float* __restrict__ K,
    const float* __restrict__ V, float* __restrict__ O)
{
    const int bh = blockIdx.y;
    const int b  = bh >> 4;
    const int h  = bh & 15;
    const int q0 = blockIdx.x * QB;
    const int t  = threadIdx.x;
    const int row = q0 + t;

    const float* Qb = Q + (size_t)bh * SEQ * D_HEAD;
    const float* Kb = K + (size_t)bh * SEQ * D_HEAD;
    const float* Vb = V + (size_t)bh * SEQ * D_HEAD;

    __shared__ float Ks[KVT][D_HEAD];
    __shared__ float Vs[KVT][D_HEAD];

    float q[D_HEAD], o[D_HEAD];
#pragma unroll
    for (int d = 0; d < D_HEAD; d += 4) {
        float4 qq = *(const float4*)&Qb[(size_t)row * D_HEAD + d];
        q[d]=qq.x*0.125f; q[d+1]=qq.y*0.125f; q[d+2]=qq.z*0.125f; q[d+3]=qq.w*0.125f;
        o[d]=0.f; o[d+1]=0.f; o[d+2]=0.f; o[d+3]=0.f;
    }

    float m = -INFINITY, l = 0.f;

    const int jload = t >> 2;         // 0..31
    const int dload = (t & 3) * 16;   // 0,16,32,48

    const int kv_end = q0 + QB;       // causal bound for this block
    for (int kv0 = 0; kv0 < kv_end; kv0 += KVT) {
        __syncthreads();
#pragma unroll
        for (int u = 0; u < 16; u += 4) {
            *(float4*)&Ks[jload][dload+u] = *(const float4*)&Kb[(size_t)(kv0+jload)*D_HEAD + dload + u];
            *(float4*)&Vs[jload][dload+u] = *(const float4*)&Vb[(size_t)(kv0+jload)*D_HEAD + dload + u];
        }
        __syncthreads();

        float s[KVT];
#pragma unroll
        for (int j = 0; j < KVT; ++j) {
            float a = 0.f;
#pragma unroll
            for (int d4 = 0; d4 < D_HEAD; d4 += 4) {
                float4 kv = *(const float4*)&Ks[j][d4];   // wave-uniform broadcast
                a = fmaf(q[d4+0], kv.x, a);
                a = fmaf(q[d4+1], kv.y, a);
                a = fmaf(q[d4+2], kv.z, a);
                a = fmaf(q[d4+3], kv.w, a);
            }
            s[j] = (kv0 + j <= row) ? a : -INFINITY;
        }

        float tmax = s[0];
#pragma unroll
        for (int j = 1; j < KVT; ++j) tmax = fmaxf(tmax, s[j]);

        if (tmax > m) {               // skip-rescale when tile max doesn't grow
            float scale = __expf(m - tmax);   // exp(-inf)=0 on first tile
            l *= scale;
#pragma unroll
            for (int d = 0; d < D_HEAD; ++d) o[d] *= scale;
            m = tmax;
        }

#pragma unroll
        for (int j = 0; j < KVT; ++j) {
            float p = __expf(s[j] - m);       // masked: exp(-inf)=0
            l += p;
#pragma unroll
            for (int d4 = 0; d4 < D_HEAD; d4 += 4) {
                float4 vv = *(const float4*)&Vs[j][d4];   // broadcast
                o[d4+0] = fmaf(p, vv.x, o[d4+0]);
                o[d4+1] = fmaf(p, vv.y, o[d4+1]);
                o[d4+2] = fmaf(p, vv.z, o[d4+2]);
                o[d4+3] = fmaf(p, vv.w, o[d4+3]);
            }
        }
    }

    const float inv = 1.f / l;
    float* dst = &O[((size_t)b * SEQ + row) * D_MODEL + h * D_HEAD];
#pragma unroll
    for (int d4 = 0; d4 < D_HEAD; d4 += 4) {
        float4 w = make_float4(o[d4]*inv, o[d4+1]*inv, o[d4+2]*inv, o[d4+3]*inv);
        *(float4*)&dst[d4] = w;
    }
}

// ---------------------------------------------------------------------------
// Kernel 3: out = LayerNorm(x + attn) * gamma + beta.  One block per row.
// ---------------------------------------------------------------------------
__global__ __launch_bounds__(256) void resid_ln(
    const float* __restrict__ X, const float* __restrict__ A,
    const float* __restrict__ gamma, const float* __restrict__ beta,
    float* __restrict__ Out)
{
    const int rowi = blockIdx.x;
    const size_t base = (size_t)rowi * D_MODEL;
    const int t = threadIdx.x;
    const int c = t * 4;

    float4 xv = *(const float4*)&X[base + c];
    float4 av = *(const float4*)&A[base + c];
    float v0 = xv.x + av.x, v1 = xv.y + av.y, v2 = xv.z + av.z, v3 = xv.w + av.w;

    float s1 = v0 + v1 + v2 + v3;
    float s2 = v0*v0 + v1*v1 + v2*v2 + v3*v3;

#pragma unroll
    for (int off = 32; off > 0; off >>= 1) {
        s1 += __shfl_down(s1, off);
        s2 += __shfl_down(s2, off);
    }

    __shared__ float r1[4], r2[4];
    __shared__ float mu_s, rstd_s;
    const int wid = t >> 6, lane = t & 63;
    if (lane == 0) { r1[wid] = s1; r2[wid] = s2; }
    __syncthreads();
    if (t == 0) {
        float S1 = r1[0]+r1[1]+r1[2]+r1[3];
        float S2 = r2[0]+r2[1]+r2[2]+r2[3];
        float mu  = S1 * (1.f/1024.f);
        float var = S2 * (1.f/1024.f) - mu*mu;
        mu_s   = mu;
        rstd_s = rsqrtf(var + 1e-5f);
    }
    __syncthreads();
    const float mu = mu_s, rstd = rstd_s;

    float4 g  = *(const float4*)&gamma[c];
    float4 be = *(const float4*)&beta[c];
    float4 ov = make_float4((v0-mu)*rstd*g.x + be.x,
                            (v1-mu)*rstd*g.y + be.y,
                            (v2-mu)*rstd*g.z + be.z,
                            (v3-mu)*rstd*g.w + be.w);
    *(float4*)&Out[base + c] = ov;
}

// ---------------------------------------------------------------------------
extern "C" void kernel_launch(void* const* d_in, const int* in_sizes, int n_in,
                              void* d_out, int out_size, void* d_ws, size_t ws_size,
                              hipStream_t stream)
{
    (void)in_sizes; (void)n_in; (void)out_size; (void)ws_size;

    const float* x     = (const float*)d_in[0];
    const float* Wq    = (const float*)d_in[1];
    const float* bq    = (const float*)d_in[2];
    const float* Wk    = (const float*)d_in[3];
    const float* bk    = (const float*)d_in[4];
    const float* Wv    = (const float*)d_in[5];
    const float* bv    = (const float*)d_in[6];
    const float* gamma = (const float*)d_in[7];
    const float* beta  = (const float*)d_in[8];

    float* out  = (float*)d_out;                     // (B,S,D)   8388608 floats
    float* kout = out  + (size_t)MTOT * D_MODEL;     // (B,H,S,dh)
    float* vout = kout + (size_t)MTOT * D_MODEL;     // (B,H,S,dh)
    float* qtmp = out;            // park q in the out-region; LN overwrites it last
    float* attn = (float*)d_ws;   // 32 MiB scratch, (B,S,D)

    dim3 gemm_grid(D_MODEL / BN, MTOT / BM);         // (8, 64) = 512 blocks
    qkv_gemm<<<gemm_grid, 256, 0, stream>>>(x, Wq, bq, qtmp);
    qkv_gemm<<<gemm_grid, 256, 0, stream>>>(x, Wk, bk, kout);
    qkv_gemm<<<gemm_grid, 256, 0, stream>>>(x, Wv, bv, vout);

    attn_fwd<<<dim3(SEQ / QB, BATCH * NUM_HEAD), 128, 0, stream>>>(qtmp, kout, vout, attn);

    resid_ln<<<MTOT, 256, 0, stream>>>(x, attn, gamma, beta, out);
}

// Round 2
// 906.540 us; speedup vs baseline: 2.1565x; 2.1565x over previous
//
#include <hip/hip_runtime.h>
#include <math.h>

#define D_MODEL 1024
#define NUM_HEAD 16
#define D_HEAD   64
#define BATCH    4
#define SEQ      2048
#define MTOT     (BATCH*SEQ)   // 8192 rows

typedef __attribute__((ext_vector_type(8))) short short8;
typedef __attribute__((ext_vector_type(4))) short short4v;
typedef __attribute__((ext_vector_type(2))) short short2v;
typedef __attribute__((ext_vector_type(4))) float f32x4;

static __device__ __forceinline__ short f2bf(float f) {
    union { float f; unsigned u; } v; v.f = f;
    unsigned r = (v.u + 0x7FFFu + ((v.u >> 16) & 1u)) >> 16;  // RNE
    return (short)r;
}

// ---------------------------------------------------------------------------
// Kernel 1: fp32 tiled GEMM  Y = X @ W + bias, output scattered to (B,H,S,dh)
// (unchanged from R1 — passed; bf16-split conversion is a later round)
// ---------------------------------------------------------------------------
#define BM 128
#define BN 128
#define BKT 16
#define LDP (BM + 4)

__global__ __launch_bounds__(256) void qkv_gemm(
    const float* __restrict__ X, const float* __restrict__ W,
    const float* __restrict__ bias, float* __restrict__ Y)
{
    __shared__ float As[BKT][LDP];
    __shared__ float Bs[BKT][LDP];

    const int t  = threadIdx.x;
    const int tx = t & 15;
    const int ty = t >> 4;
    const int m0 = blockIdx.y * BM;
    const int n0 = blockIdx.x * BN;

    float acc[8][8];
#pragma unroll
    for (int i = 0; i < 8; ++i)
#pragma unroll
        for (int j = 0; j < 8; ++j) acc[i][j] = 0.f;

    const int am = t >> 1;
    const int ak = (t & 1) * 8;
    const int bkr = t >> 4;
    const int bn  = (t & 15) * 4;

    for (int k0 = 0; k0 < D_MODEL; k0 += BKT) {
        float4 a0 = *(const float4*)&X[(size_t)(m0 + am) * D_MODEL + k0 + ak];
        float4 a1 = *(const float4*)&X[(size_t)(m0 + am) * D_MODEL + k0 + ak + 4];
        float4 b0 = *(const float4*)&W[(size_t)(k0 + bkr) * D_MODEL + n0 + bn];
        float4 b1 = *(const float4*)&W[(size_t)(k0 + bkr) * D_MODEL + n0 + bn + 64];
        __syncthreads();
        As[ak+0][am] = a0.x; As[ak+1][am] = a0.y; As[ak+2][am] = a0.z; As[ak+3][am] = a0.w;
        As[ak+4][am] = a1.x; As[ak+5][am] = a1.y; As[ak+6][am] = a1.z; As[ak+7][am] = a1.w;
        *(float4*)&Bs[bkr][bn]      = b0;
        *(float4*)&Bs[bkr][bn + 64] = b1;
        __syncthreads();
#pragma unroll
        for (int k = 0; k < BKT; ++k) {
            float4 av0 = *(const float4*)&As[k][ty*8];
            float4 av1 = *(const float4*)&As[k][ty*8+4];
            float4 bv0 = *(const float4*)&Bs[k][tx*8];
            float4 bv1 = *(const float4*)&Bs[k][tx*8+4];
            float a[8] = {av0.x,av0.y,av0.z,av0.w,av1.x,av1.y,av1.z,av1.w};
            float b[8] = {bv0.x,bv0.y,bv0.z,bv0.w,bv1.x,bv1.y,bv1.z,bv1.w};
#pragma unroll
            for (int i = 0; i < 8; ++i)
#pragma unroll
                for (int j = 0; j < 8; ++j)
                    acc[i][j] = fmaf(a[i], b[j], acc[i][j]);
        }
    }

    const int gn = n0 + tx*8;
    const int h  = gn >> 6;
    const int dl = gn & 63;
    float bb[8];
#pragma unroll
    for (int j = 0; j < 8; ++j) bb[j] = bias[gn + j];

#pragma unroll
    for (int i = 0; i < 8; ++i) {
        int row  = m0 + ty*8 + i;
        int bidx = row >> 11;
        int srow = row & (SEQ - 1);
        float* dst = &Y[(((size_t)bidx*NUM_HEAD + h)*SEQ + srow)*D_HEAD + dl];
        float4 w0 = make_float4(acc[i][0]+bb[0], acc[i][1]+bb[1], acc[i][2]+bb[2], acc[i][3]+bb[3]);
        float4 w1 = make_float4(acc[i][4]+bb[4], acc[i][5]+bb[5], acc[i][6]+bb[6], acc[i][7]+bb[7]);
        *(float4*)&dst[0] = w0;
        *(float4*)&dst[4] = w1;
    }
}

// ---------------------------------------------------------------------------
// Kernel 2: causal flash attention with bf16 MFMA (16x16x32), fp32 accum.
// 8 waves/block, 128 q-rows/block (16/wave). KV tiles of 64 in LDS bf16:
//   Ks  [64 kv][64 d]  bytes [0,8192)      XOR-swizzled ((row&7)<<4)
//   VT  [64 d][64 kv]  bytes [8192,16384)  XOR-swizzled (transposed at staging)
//   P   per-wave [16 q][64 kv] bytes 16384 + w*2048 (wave-private, no barrier)
// Swapped QK^T: S^T = K·Q^T so softmax row q = lane&15. Online softmax;
// lsum kept lane-partial, reduced once at the end.
// ---------------------------------------------------------------------------
__global__ __launch_bounds__(512) void attn_mfma(
    const float* __restrict__ Q, const float* __restrict__ K,
    const float* __restrict__ V, float* __restrict__ O)
{
    __shared__ char smem[32*1024];
    const int t  = threadIdx.x;
    const int w  = t >> 6;
    const int l  = t & 63;
    const int lq = l & 15;
    const int g  = l >> 4;

    const int bh = blockIdx.y;
    const int q0 = blockIdx.x * 128;
    const float* Qb = Q + (size_t)bh * SEQ * D_HEAD;
    const float* Kb = K + (size_t)bh * SEQ * D_HEAD;
    const float* Vb = V + (size_t)bh * SEQ * D_HEAD;

    const int qrow = q0 + w*16 + lq;

    // Q fragments: lane l holds Q[qrow][32c + g*8 + j], j=0..7, scaled 1/8
    short8 qf[2];
    {
        const float* qp = &Qb[(size_t)qrow * D_HEAD];
#pragma unroll
        for (int c = 0; c < 2; ++c) {
            float4 x0 = *(const float4*)&qp[c*32 + g*8];
            float4 x1 = *(const float4*)&qp[c*32 + g*8 + 4];
            short8 f;
            f[0]=f2bf(x0.x*0.125f); f[1]=f2bf(x0.y*0.125f);
            f[2]=f2bf(x0.z*0.125f); f[3]=f2bf(x0.w*0.125f);
            f[4]=f2bf(x1.x*0.125f); f[5]=f2bf(x1.y*0.125f);
            f[6]=f2bf(x1.z*0.125f); f[7]=f2bf(x1.w*0.125f);
            qf[c] = f;
        }
    }

    f32x4 o[4];
#pragma unroll
    for (int i = 0; i < 4; ++i) { o[i][0]=0.f; o[i][1]=0.f; o[i][2]=0.f; o[i][3]=0.f; }
    float m = -INFINITY, lsum = 0.f;

    const int pbase = 16384 + w*2048;
    const int dd  = (t & 15) * 4;     // staging d-offset
    const int rot = (t >> 1) & 3;     // VT write-conflict rotation

    for (int kvb = 0; kvb <= q0 + 64; kvb += 64) {
        __syncthreads();
        // --- stage K tile (row-major bf16, swizzled) ---
#pragma unroll
        for (int u = 0; u < 2; ++u) {
            int kv = (t >> 4) + 32*u;
            float4 x = *(const float4*)&Kb[(size_t)(kvb + kv) * D_HEAD + dd];
            short4v pk; pk[0]=f2bf(x.x); pk[1]=f2bf(x.y); pk[2]=f2bf(x.z); pk[3]=f2bf(x.w);
            *(short4v*)(smem + kv*128 + ((dd*2) ^ ((kv & 7) << 4))) = pk;
        }
        // --- stage V^T tile (pair-packed bf16x2 writes, rotated) ---
        {
            int p2 = t >> 4;                        // kv pair 0..31
            float4 a = *(const float4*)&Vb[(size_t)(kvb + 2*p2    ) * D_HEAD + dd];
            float4 b = *(const float4*)&Vb[(size_t)(kvb + 2*p2 + 1) * D_HEAD + dd];
            float av[4] = {a.x, a.y, a.z, a.w};
            float bv[4] = {b.x, b.y, b.z, b.w};
#pragma unroll
            for (int j = 0; j < 4; ++j) {
                int jp  = (j + rot) & 3;
                int row = dd + jp;                  // d index = VT row
                short2v pk; pk[0] = f2bf(av[jp]); pk[1] = f2bf(bv[jp]);
                *(short2v*)(smem + 8192 + row*128 + ((p2*4) ^ ((row & 7) << 4))) = pk;
            }
        }
        __syncthreads();

        // --- S^T = K · Q^T : 4 tiles of 16 kv × 16 q ---
        f32x4 st[4];
#pragma unroll
        for (int tt = 0; tt < 4; ++tt) {
            int row = tt*16 + lq;
            const char* base = smem + row*128;
            short8 ka0 = *(const short8*)(base + ((     16*g) ^ ((row & 7) << 4)));
            short8 ka1 = *(const short8*)(base + ((64 + 16*g) ^ ((row & 7) << 4)));
            f32x4 z; z[0]=0.f; z[1]=0.f; z[2]=0.f; z[3]=0.f;
            z = __builtin_amdgcn_mfma_f32_16x16x32_bf16(ka0, qf[0], z, 0, 0, 0);
            z = __builtin_amdgcn_mfma_f32_16x16x32_bf16(ka1, qf[1], z, 0, 0, 0);
            st[tt] = z;
        }

        // --- mask + online softmax (row q = lq; kv = kvb + 16tt + 4g + r) ---
        float tmax = -INFINITY;
#pragma unroll
        for (int tt = 0; tt < 4; ++tt)
#pragma unroll
            for (int r = 0; r < 4; ++r) {
                int kv = kvb + tt*16 + g*4 + r;
                float s = (kv <= qrow) ? st[tt][r] : -INFINITY;
                st[tt][r] = s;
                tmax = fmaxf(tmax, s);
            }
        tmax = fmaxf(tmax, __shfl_xor(tmax, 16));
        tmax = fmaxf(tmax, __shfl_xor(tmax, 32));

        float mnew = fmaxf(m, tmax);
        float scl  = __expf(m - mnew);      // first tile: exp(-inf)=0
        m = mnew;
        lsum *= scl;
        // redistribute rescale to O-rows (O row i = 4g + r; source lane 20g+r)
        float sr0 = __shfl(scl, 20*g + 0);
        float sr1 = __shfl(scl, 20*g + 1);
        float sr2 = __shfl(scl, 20*g + 2);
        float sr3 = __shfl(scl, 20*g + 3);
#pragma unroll
        for (int dc = 0; dc < 4; ++dc) {
            o[dc][0] *= sr0; o[dc][1] *= sr1; o[dc][2] *= sr2; o[dc][3] *= sr3;
        }

        // --- P = exp(S^T - m), lane-partial lsum, pack to wave-private LDS ---
#pragma unroll
        for (int tt = 0; tt < 4; ++tt) {
            float p0 = __expf(st[tt][0] - mnew);
            float p1 = __expf(st[tt][1] - mnew);
            float p2f= __expf(st[tt][2] - mnew);
            float p3 = __expf(st[tt][3] - mnew);
            lsum += (p0 + p1) + (p2f + p3);
            short4v pk; pk[0]=f2bf(p0); pk[1]=f2bf(p1); pk[2]=f2bf(p2f); pk[3]=f2bf(p3);
            *(short4v*)(smem + pbase + lq*128 + ((32*tt + 8*g) ^ ((lq & 7) << 4))) = pk;
        }

        // --- O += P · V  (A-frag from P_lds, B-frag from VT; DS wave-ordered) ---
        short8 pa0 = *(const short8*)(smem + pbase + lq*128 + ((     16*g) ^ ((lq & 7) << 4)));
        short8 pa1 = *(const short8*)(smem + pbase + lq*128 + ((64 + 16*g) ^ ((lq & 7) << 4)));
#pragma unroll
        for (int dc = 0; dc < 4; ++dc) {
            int row = dc*16 + lq;
            const char* vb = smem + 8192 + row*128;
            short8 v0 = *(const short8*)(vb + ((     16*g) ^ ((row & 7) << 4)));
            short8 v1 = *(const short8*)(vb + ((64 + 16*g) ^ ((row & 7) << 4)));
            o[dc] = __builtin_amdgcn_mfma_f32_16x16x32_bf16(pa0, v0, o[dc], 0, 0, 0);
            o[dc] = __builtin_amdgcn_mfma_f32_16x16x32_bf16(pa1, v1, o[dc], 0, 0, 0);
        }
    }

    // --- finalize: reduce lsum across groups, divide, store (B,S,D) ---
    lsum += __shfl_xor(lsum, 16);
    lsum += __shfl_xor(lsum, 32);
    float linv = 1.f / lsum;
    float lr0 = __shfl(linv, 20*g + 0);
    float lr1 = __shfl(linv, 20*g + 1);
    float lr2 = __shfl(linv, 20*g + 2);
    float lr3 = __shfl(linv, 20*g + 3);

    const int b = bh >> 4, h = bh & 15;
    float* Ob = O + ((size_t)b * SEQ + q0 + w*16) * D_MODEL + h * D_HEAD;
#pragma unroll
    for (int dc = 0; dc < 4; ++dc) {
        int col = dc*16 + lq;
        Ob[(4*g + 0)*D_MODEL + col] = o[dc][0] * lr0;
        Ob[(4*g + 1)*D_MODEL + col] = o[dc][1] * lr1;
        Ob[(4*g + 2)*D_MODEL + col] = o[dc][2] * lr2;
        Ob[(4*g + 3)*D_MODEL + col] = o[dc][3] * lr3;
    }
}

// ---------------------------------------------------------------------------
// Kernel 3: out = LayerNorm(x + attn) * gamma + beta.  (unchanged from R1)
// ---------------------------------------------------------------------------
__global__ __launch_bounds__(256) void resid_ln(
    const float* __restrict__ X, const float* __restrict__ A,
    const float* __restrict__ gamma, const float* __restrict__ beta,
    float* __restrict__ Out)
{
    const int rowi = blockIdx.x;
    const size_t base = (size_t)rowi * D_MODEL;
    const int t = threadIdx.x;
    const int c = t * 4;

    float4 xv = *(const float4*)&X[base + c];
    float4 av = *(const float4*)&A[base + c];
    float v0 = xv.x + av.x, v1 = xv.y + av.y, v2 = xv.z + av.z, v3 = xv.w + av.w;

    float s1 = v0 + v1 + v2 + v3;
    float s2 = v0*v0 + v1*v1 + v2*v2 + v3*v3;

#pragma unroll
    for (int off = 32; off > 0; off >>= 1) {
        s1 += __shfl_down(s1, off);
        s2 += __shfl_down(s2, off);
    }

    __shared__ float r1[4], r2[4];
    __shared__ float mu_s, rstd_s;
    const int wid = t >> 6, lane = t & 63;
    if (lane == 0) { r1[wid] = s1; r2[wid] = s2; }
    __syncthreads();
    if (t == 0) {
        float S1 = r1[0]+r1[1]+r1[2]+r1[3];
        float S2 = r2[0]+r2[1]+r2[2]+r2[3];
        float mu  = S1 * (1.f/1024.f);
        float var = S2 * (1.f/1024.f) - mu*mu;
        mu_s   = mu;
        rstd_s = rsqrtf(var + 1e-5f);
    }
    __syncthreads();
    const float mu = mu_s, rstd = rstd_s;

    float4 gq = *(const float4*)&gamma[c];
    float4 be = *(const float4*)&beta[c];
    float4 ov = make_float4((v0-mu)*rstd*gq.x + be.x,
                            (v1-mu)*rstd*gq.y + be.y,
                            (v2-mu)*rstd*gq.z + be.z,
                            (v3-mu)*rstd*gq.w + be.w);
    *(float4*)&Out[base + c] = ov;
}

// ---------------------------------------------------------------------------
extern "C" void kernel_launch(void* const* d_in, const int* in_sizes, int n_in,
                              void* d_out, int out_size, void* d_ws, size_t ws_size,
                              hipStream_t stream)
{
    (void)in_sizes; (void)n_in; (void)out_size; (void)ws_size;

    const float* x     = (const float*)d_in[0];
    const float* Wq    = (const float*)d_in[1];
    const float* bq    = (const float*)d_in[2];
    const float* Wk    = (const float*)d_in[3];
    const float* bk    = (const float*)d_in[4];
    const float* Wv    = (const float*)d_in[5];
    const float* bv    = (const float*)d_in[6];
    const float* gamma = (const float*)d_in[7];
    const float* beta  = (const float*)d_in[8];

    float* out  = (float*)d_out;
    float* kout = out  + (size_t)MTOT * D_MODEL;
    float* vout = kout + (size_t)MTOT * D_MODEL;
    float* qtmp = out;            // park q in out-region; LN overwrites it last
    float* attn = (float*)d_ws;   // (B,S,D) fp32 scratch

    dim3 gemm_grid(D_MODEL / BN, MTOT / BM);
    qkv_gemm<<<gemm_grid, 256, 0, stream>>>(x, Wq, bq, qtmp);
    qkv_gemm<<<gemm_grid, 256, 0, stream>>>(x, Wk, bk, kout);
    qkv_gemm<<<gemm_grid, 256, 0, stream>>>(x, Wv, bv, vout);

    attn_mfma<<<dim3(SEQ / 128, BATCH * NUM_HEAD), 512, 0, stream>>>(qtmp, kout, vout, attn);

    resid_ln<<<MTOT, 256, 0, stream>>>(x, attn, gamma, beta, out);
}

// Round 4
// 472.521 us; speedup vs baseline: 4.1373x; 1.9185x over previous
//
#include <hip/hip_runtime.h>
#include <math.h>

#define D_MODEL 1024
#define NUM_HEAD 16
#define D_HEAD   64
#define BATCH    4
#define SEQ      2048
#define MTOT     (BATCH*SEQ)   // 8192 rows

typedef __attribute__((ext_vector_type(8))) short short8;
typedef __attribute__((ext_vector_type(4))) short short4v;
typedef __attribute__((ext_vector_type(2))) short short2v;
typedef __attribute__((ext_vector_type(4))) float f32x4;

static __device__ __forceinline__ unsigned short f2bf_u(float f) {
    union { float f; unsigned u; } v; v.f = f;
    return (unsigned short)((v.u + 0x7FFFu + ((v.u >> 16) & 1u)) >> 16);  // RNE
}
static __device__ __forceinline__ short f2bf(float f) { return (short)f2bf_u(f); }
static __device__ __forceinline__ float bf2f(unsigned short h) {
    union { float f; unsigned u; } v; v.u = ((unsigned)h) << 16; return v.f;
}

// async 16B global->LDS
#define ASYNC16(ldst, gsrc) __builtin_amdgcn_global_load_lds( \
    (const __attribute__((address_space(1))) unsigned int*)(gsrc), \
    (__attribute__((address_space(3))) unsigned int*)(ldst), 16, 0, 0)

// ---------------------------------------------------------------------------
// conv_x: x rows [m0, m0+mcnt) fp32 -> hi/lo bf16, tile-packed
// layout: [mtile_local][kstep 32][128 m][32 k], 4096 elts per tile
// one thread per 8 elements.
// ---------------------------------------------------------------------------
__global__ __launch_bounds__(256) void conv_x(
    const float* __restrict__ x, unsigned short* __restrict__ hi,
    unsigned short* __restrict__ lo, int m0)
{
    const int gid = blockIdx.x * 256 + threadIdx.x;
    const int ml = gid >> 7;            // local row
    const int k  = (gid & 127) << 3;
    const float* s = &x[(size_t)(m0 + ml) * D_MODEL + k];
    float4 a = *(const float4*)s;
    float4 b = *(const float4*)(s + 4);
    float vv[8] = {a.x, a.y, a.z, a.w, b.x, b.y, b.z, b.w};
    short8 ph, pl;
#pragma unroll
    for (int j = 0; j < 8; ++j) {
        unsigned short h = f2bf_u(vv[j]);
        ph[j] = (short)h;
        pl[j] = (short)f2bf_u(vv[j] - bf2f(h));
    }
    size_t off = ((size_t)(ml >> 7) * 32 + (k >> 5)) * 4096
               + (size_t)(ml & 127) * 32 + (k & 31);
    *(short8*)&hi[off] = ph;
    *(short8*)&lo[off] = pl;
}

// ---------------------------------------------------------------------------
// conv_w: W [1024 k][1024 n] fp32 -> W^T hi/lo bf16, tile-packed n-major
// layout: [ntile 8][kstep 32][128 n][32 k]. Transpose via LDS.
// grid (8 ntiles, 32 ksteps), 256 threads.
// ---------------------------------------------------------------------------
__global__ __launch_bounds__(256) void conv_w(
    const float* __restrict__ W, unsigned short* __restrict__ hi,
    unsigned short* __restrict__ lo)
{
    __shared__ float Tr[32][132];
    const int t  = threadIdx.x;
    const int n0 = blockIdx.x * 128, k0 = blockIdx.y * 32;
#pragma unroll
    for (int it = 0; it < 4; ++it) {
        int idx = it * 256 + t;
        int kr = idx >> 5, c = (idx & 31) * 4;
        *(float4*)&Tr[kr][c] = *(const float4*)&W[(size_t)(k0 + kr) * D_MODEL + n0 + c];
    }
    __syncthreads();
    const int n = t >> 1, kh = (t & 1) * 16;
    short8 ph0, ph1, pl0, pl1;
#pragma unroll
    for (int j = 0; j < 16; ++j) {
        float v = Tr[kh + j][n];
        unsigned short h = f2bf_u(v);
        unsigned short lw = f2bf_u(v - bf2f(h));
        if (j < 8) { ph0[j] = (short)h; pl0[j] = (short)lw; }
        else       { ph1[j - 8] = (short)h; pl1[j - 8] = (short)lw; }
    }
    size_t base = ((size_t)blockIdx.x * 32 + blockIdx.y) * 4096 + (size_t)n * 32 + kh;
    *(short8*)&hi[base]     = ph0;
    *(short8*)&hi[base + 8] = ph1;
    *(short8*)&lo[base]     = pl0;
    *(short8*)&lo[base + 8] = pl1;
}

// ---------------------------------------------------------------------------
// gemm3: C = (Ah+Al) @ (Bh+Bl)^T + bias via 3-term split bf16 MFMA.
// A packs [mtiles][32][128 m][32 k]; B packs [8 ntiles][32][128 n][32 k].
// 128x128 block, 4 waves (2x2 of 64x64), BK=32, 16x16x32 MFMA.
// Output scattered to (B,H,S,dh) fp32.
// ---------------------------------------------------------------------------
__global__ __launch_bounds__(256) void gemm3(
    const unsigned short* __restrict__ Ah, const unsigned short* __restrict__ Al,
    const unsigned short* __restrict__ Bh, const unsigned short* __restrict__ Bl,
    const float* __restrict__ bias, float* __restrict__ Y, int m0)
{
    __shared__ unsigned short lds[16384];   // 32 KB: Ah | Bh | Al | Bl (4096 each)
    unsigned short* LA  = lds;
    unsigned short* LB  = lds + 4096;
    unsigned short* LAl = lds + 8192;
    unsigned short* LBl = lds + 12288;

    const int t  = threadIdx.x;
    const int l  = t & 63, w = t >> 6;
    const int lq = l & 15, g = l >> 4;
    const int wr = w >> 1, wc = w & 1;

    const size_t abase = (size_t)blockIdx.y * 32 * 4096;
    const size_t bbase = (size_t)blockIdx.x * 32 * 4096;

    f32x4 acc[4][4];
#pragma unroll
    for (int i = 0; i < 4; ++i)
#pragma unroll
        for (int j = 0; j < 4; ++j) { acc[i][j][0]=0.f; acc[i][j][1]=0.f; acc[i][j][2]=0.f; acc[i][j][3]=0.f; }

    for (int ks = 0; ks < 32; ++ks) {
        const unsigned short* ga  = Ah + abase + (size_t)ks * 4096;
        const unsigned short* gal = Al + abase + (size_t)ks * 4096;
        const unsigned short* gb  = Bh + bbase + (size_t)ks * 4096;
        const unsigned short* gbl = Bl + bbase + (size_t)ks * 4096;
        __syncthreads();
        ASYNC16(&LA [t*8],        ga  + t*8);
        ASYNC16(&LA [2048 + t*8], ga  + 2048 + t*8);
        ASYNC16(&LB [t*8],        gb  + t*8);
        ASYNC16(&LB [2048 + t*8], gb  + 2048 + t*8);
        ASYNC16(&LAl[t*8],        gal + t*8);
        ASYNC16(&LAl[2048 + t*8], gal + 2048 + t*8);
        ASYNC16(&LBl[t*8],        gbl + t*8);
        ASYNC16(&LBl[2048 + t*8], gbl + 2048 + t*8);
        __syncthreads();

        short8 ah[4], al[4];
#pragma unroll
        for (int fm = 0; fm < 4; ++fm) {
            int off = (wr*64 + fm*16 + lq) * 32 + g*8;
            ah[fm] = *(const short8*)&LA [off];
            al[fm] = *(const short8*)&LAl[off];
        }
#pragma unroll
        for (int fn = 0; fn < 4; ++fn) {
            int off = (wc*64 + fn*16 + lq) * 32 + g*8;
            short8 bh = *(const short8*)&LB [off];
            short8 bl = *(const short8*)&LBl[off];
#pragma unroll
            for (int fm = 0; fm < 4; ++fm) {
                acc[fm][fn] = __builtin_amdgcn_mfma_f32_16x16x32_bf16(ah[fm], bh, acc[fm][fn], 0, 0, 0);
                acc[fm][fn] = __builtin_amdgcn_mfma_f32_16x16x32_bf16(al[fm], bh, acc[fm][fn], 0, 0, 0);
                acc[fm][fn] = __builtin_amdgcn_mfma_f32_16x16x32_bf16(ah[fm], bl, acc[fm][fn], 0, 0, 0);
            }
        }
    }

    // epilogue: bias + scatter to (B,H,S,dh)
    const int nb = blockIdx.x*128 + wc*64;
#pragma unroll
    for (int fn = 0; fn < 4; ++fn) {
        int n = nb + fn*16 + lq;
        int h = n >> 6, dl = n & 63;
        float bv = bias[n];
#pragma unroll
        for (int fm = 0; fm < 4; ++fm) {
            int mg = m0 + blockIdx.y*128 + wr*64 + fm*16 + g*4;
#pragma unroll
            for (int r = 0; r < 4; ++r) {
                int m  = mg + r;
                int bi = m >> 11, sr = m & (SEQ - 1);
                Y[(((size_t)bi*NUM_HEAD + h)*SEQ + sr)*D_HEAD + dl] = acc[fm][fn][r] + bv;
            }
        }
    }
}

// ---------------------------------------------------------------------------
// attn_mfma: causal flash attention, bf16 MFMA, fp32 accum (unchanged from R2)
// ---------------------------------------------------------------------------
__global__ __launch_bounds__(512) void attn_mfma(
    const float* __restrict__ Q, const float* __restrict__ K,
    const float* __restrict__ V, float* __restrict__ O)
{
    __shared__ char smem[32*1024];
    const int t  = threadIdx.x;
    const int w  = t >> 6;
    const int l  = t & 63;
    const int lq = l & 15;
    const int g  = l >> 4;

    const int bh = blockIdx.y;
    const int q0 = blockIdx.x * 128;
    const float* Qb = Q + (size_t)bh * SEQ * D_HEAD;
    const float* Kb = K + (size_t)bh * SEQ * D_HEAD;
    const float* Vb = V + (size_t)bh * SEQ * D_HEAD;

    const int qrow = q0 + w*16 + lq;

    short8 qf[2];
    {
        const float* qp = &Qb[(size_t)qrow * D_HEAD];
#pragma unroll
        for (int c = 0; c < 2; ++c) {
            float4 x0 = *(const float4*)&qp[c*32 + g*8];
            float4 x1 = *(const float4*)&qp[c*32 + g*8 + 4];
            short8 f;
            f[0]=f2bf(x0.x*0.125f); f[1]=f2bf(x0.y*0.125f);
            f[2]=f2bf(x0.z*0.125f); f[3]=f2bf(x0.w*0.125f);
            f[4]=f2bf(x1.x*0.125f); f[5]=f2bf(x1.y*0.125f);
            f[6]=f2bf(x1.z*0.125f); f[7]=f2bf(x1.w*0.125f);
            qf[c] = f;
        }
    }

    f32x4 o[4];
#pragma unroll
    for (int i = 0; i < 4; ++i) { o[i][0]=0.f; o[i][1]=0.f; o[i][2]=0.f; o[i][3]=0.f; }
    float m = -INFINITY, lsum = 0.f;

    const int pbase = 16384 + w*2048;
    const int dd  = (t & 15) * 4;
    const int rot = (t >> 1) & 3;

    for (int kvb = 0; kvb <= q0 + 64; kvb += 64) {
        __syncthreads();
#pragma unroll
        for (int u = 0; u < 2; ++u) {
            int kv = (t >> 4) + 32*u;
            float4 x = *(const float4*)&Kb[(size_t)(kvb + kv) * D_HEAD + dd];
            short4v pk; pk[0]=f2bf(x.x); pk[1]=f2bf(x.y); pk[2]=f2bf(x.z); pk[3]=f2bf(x.w);
            *(short4v*)(smem + kv*128 + ((dd*2) ^ ((kv & 7) << 4))) = pk;
        }
        {
            int p2 = t >> 4;
            float4 a = *(const float4*)&Vb[(size_t)(kvb + 2*p2    ) * D_HEAD + dd];
            float4 b = *(const float4*)&Vb[(size_t)(kvb + 2*p2 + 1) * D_HEAD + dd];
            float av[4] = {a.x, a.y, a.z, a.w};
            float bv[4] = {b.x, b.y, b.z, b.w};
#pragma unroll
            for (int j = 0; j < 4; ++j) {
                int jp  = (j + rot) & 3;
                int row = dd + jp;
                short2v pk; pk[0] = f2bf(av[jp]); pk[1] = f2bf(bv[jp]);
                *(short2v*)(smem + 8192 + row*128 + ((p2*4) ^ ((row & 7) << 4))) = pk;
            }
        }
        __syncthreads();

        f32x4 st[4];
#pragma unroll
        for (int tt = 0; tt < 4; ++tt) {
            int row = tt*16 + lq;
            const char* base = smem + row*128;
            short8 ka0 = *(const short8*)(base + ((     16*g) ^ ((row & 7) << 4)));
            short8 ka1 = *(const short8*)(base + ((64 + 16*g) ^ ((row & 7) << 4)));
            f32x4 z; z[0]=0.f; z[1]=0.f; z[2]=0.f; z[3]=0.f;
            z = __builtin_amdgcn_mfma_f32_16x16x32_bf16(ka0, qf[0], z, 0, 0, 0);
            z = __builtin_amdgcn_mfma_f32_16x16x32_bf16(ka1, qf[1], z, 0, 0, 0);
            st[tt] = z;
        }

        float tmax = -INFINITY;
#pragma unroll
        for (int tt = 0; tt < 4; ++tt)
#pragma unroll
            for (int r = 0; r < 4; ++r) {
                int kv = kvb + tt*16 + g*4 + r;
                float s = (kv <= qrow) ? st[tt][r] : -INFINITY;
                st[tt][r] = s;
                tmax = fmaxf(tmax, s);
            }
        tmax = fmaxf(tmax, __shfl_xor(tmax, 16));
        tmax = fmaxf(tmax, __shfl_xor(tmax, 32));

        float mnew = fmaxf(m, tmax);
        float scl  = __expf(m - mnew);
        m = mnew;
        lsum *= scl;
        float sr0 = __shfl(scl, 20*g + 0);
        float sr1 = __shfl(scl, 20*g + 1);
        float sr2 = __shfl(scl, 20*g + 2);
        float sr3 = __shfl(scl, 20*g + 3);
#pragma unroll
        for (int dc = 0; dc < 4; ++dc) {
            o[dc][0] *= sr0; o[dc][1] *= sr1; o[dc][2] *= sr2; o[dc][3] *= sr3;
        }

#pragma unroll
        for (int tt = 0; tt < 4; ++tt) {
            float p0 = __expf(st[tt][0] - mnew);
            float p1 = __expf(st[tt][1] - mnew);
            float p2f= __expf(st[tt][2] - mnew);
            float p3 = __expf(st[tt][3] - mnew);
            lsum += (p0 + p1) + (p2f + p3);
            short4v pk; pk[0]=f2bf(p0); pk[1]=f2bf(p1); pk[2]=f2bf(p2f); pk[3]=f2bf(p3);
            *(short4v*)(smem + pbase + lq*128 + ((32*tt + 8*g) ^ ((lq & 7) << 4))) = pk;
        }

        short8 pa0 = *(const short8*)(smem + pbase + lq*128 + ((     16*g) ^ ((lq & 7) << 4)));
        short8 pa1 = *(const short8*)(smem + pbase + lq*128 + ((64 + 16*g) ^ ((lq & 7) << 4)));
#pragma unroll
        for (int dc = 0; dc < 4; ++dc) {
            int row = dc*16 + lq;
            const char* vb = smem + 8192 + row*128;
            short8 v0 = *(const short8*)(vb + ((     16*g) ^ ((row & 7) << 4)));
            short8 v1 = *(const short8*)(vb + ((64 + 16*g) ^ ((row & 7) << 4)));
            o[dc] = __builtin_amdgcn_mfma_f32_16x16x32_bf16(pa0, v0, o[dc], 0, 0, 0);
            o[dc] = __builtin_amdgcn_mfma_f32_16x16x32_bf16(pa1, v1, o[dc], 0, 0, 0);
        }
    }

    lsum += __shfl_xor(lsum, 16);
    lsum += __shfl_xor(lsum, 32);
    float linv = 1.f / lsum;
    float lr0 = __shfl(linv, 20*g + 0);
    float lr1 = __shfl(linv, 20*g + 1);
    float lr2 = __shfl(linv, 20*g + 2);
    float lr3 = __shfl(linv, 20*g + 3);

    const int b = bh >> 4, h = bh & 15;
    float* Ob = O + ((size_t)b * SEQ + q0 + w*16) * D_MODEL + h * D_HEAD;
#pragma unroll
    for (int dc = 0; dc < 4; ++dc) {
        int col = dc*16 + lq;
        Ob[(4*g + 0)*D_MODEL + col] = o[dc][0] * lr0;
        Ob[(4*g + 1)*D_MODEL + col] = o[dc][1] * lr1;
        Ob[(4*g + 2)*D_MODEL + col] = o[dc][2] * lr2;
        Ob[(4*g + 3)*D_MODEL + col] = o[dc][3] * lr3;
    }
}

// ---------------------------------------------------------------------------
// resid_ln (unchanged from R2)
// ---------------------------------------------------------------------------
__global__ __launch_bounds__(256) void resid_ln(
    const float* __restrict__ X, const float* __restrict__ A,
    const float* __restrict__ gamma, const float* __restrict__ beta,
    float* __restrict__ Out)
{
    const int rowi = blockIdx.x;
    const size_t base = (size_t)rowi * D_MODEL;
    const int t = threadIdx.x;
    const int c = t * 4;

    float4 xv = *(const float4*)&X[base + c];
    float4 av = *(const float4*)&A[base + c];
    float v0 = xv.x + av.x, v1 = xv.y + av.y, v2 = xv.z + av.z, v3 = xv.w + av.w;

    float s1 = v0 + v1 + v2 + v3;
    float s2 = v0*v0 + v1*v1 + v2*v2 + v3*v3;

#pragma unroll
    for (int off = 32; off > 0; off >>= 1) {
        s1 += __shfl_down(s1, off);
        s2 += __shfl_down(s2, off);
    }

    __shared__ float r1[4], r2[4];
    __shared__ float mu_s, rstd_s;
    const int wid = t >> 6, lane = t & 63;
    if (lane == 0) { r1[wid] = s1; r2[wid] = s2; }
    __syncthreads();
    if (t == 0) {
        float S1 = r1[0]+r1[1]+r1[2]+r1[3];
        float S2 = r2[0]+r2[1]+r2[2]+r2[3];
        float mu  = S1 * (1.f/1024.f);
        float var = S2 * (1.f/1024.f) - mu*mu;
        mu_s   = mu;
        rstd_s = rsqrtf(var + 1e-5f);
    }
    __syncthreads();
    const float mu = mu_s, rstd = rstd_s;

    float4 gq = *(const float4*)&gamma[c];
    float4 be = *(const float4*)&beta[c];
    float4 ov = make_float4((v0-mu)*rstd*gq.x + be.x,
                            (v1-mu)*rstd*gq.y + be.y,
                            (v2-mu)*rstd*gq.z + be.z,
                            (v3-mu)*rstd*gq.w + be.w);
    *(float4*)&Out[base + c] = ov;
}

// ---------------------------------------------------------------------------
extern "C" void kernel_launch(void* const* d_in, const int* in_sizes, int n_in,
                              void* d_out, int out_size, void* d_ws, size_t ws_size,
                              hipStream_t stream)
{
    (void)in_sizes; (void)n_in; (void)out_size;

    const float* x     = (const float*)d_in[0];
    const float* Wq    = (const float*)d_in[1];
    const float* bq    = (const float*)d_in[2];
    const float* Wk    = (const float*)d_in[3];
    const float* bk    = (const float*)d_in[4];
    const float* Wv    = (const float*)d_in[5];
    const float* bv    = (const float*)d_in[6];
    const float* gamma = (const float*)d_in[7];
    const float* beta  = (const float*)d_in[8];

    float* out  = (float*)d_out;
    float* kout = out  + (size_t)MTOT * D_MODEL;
    float* vout = kout + (size_t)MTOT * D_MODEL;
    float* qtmp = out;             // park q (B,H,S,dh) in out-region; LN overwrites last
    float* attn = (float*)d_ws;    // aliases packs; used only after GEMMs complete

    // ws: x packs (hi+lo) then 6 W packs of 1M ushorts each.
    const size_t W_ELT  = (size_t)D_MODEL * D_MODEL;             // 1<<20
    const size_t need_full = (size_t)MTOT*D_MODEL*2*2 + 6*W_ELT*2;  // 46,137,344 B
    const int nh = (ws_size >= need_full) ? 1 : 2;               // half-mode fits proven 33.5MB
    const int HM = MTOT / nh;

    unsigned short* xh  = (unsigned short*)d_ws;
    unsigned short* xl  = xh + (size_t)HM * D_MODEL;
    unsigned short* wp  = xl + (size_t)HM * D_MODEL;
    unsigned short* wqh = wp;             unsigned short* wql = wqh + W_ELT;
    unsigned short* wkh = wql + W_ELT;    unsigned short* wkl = wkh + W_ELT;
    unsigned short* wvh = wkl + W_ELT;    unsigned short* wvl = wvh + W_ELT;

    conv_w<<<dim3(8, 32), 256, 0, stream>>>(Wq, wqh, wql);
    conv_w<<<dim3(8, 32), 256, 0, stream>>>(Wk, wkh, wkl);
    conv_w<<<dim3(8, 32), 256, 0, stream>>>(Wv, wvh, wvl);

    for (int hh = 0; hh < nh; ++hh) {
        const int m0 = hh * HM;
        conv_x<<<HM / 2, 256, 0, stream>>>(x, xh, xl, m0);
        dim3 gg(8, HM / 128);
        gemm3<<<gg, 256, 0, stream>>>(xh, xl, wqh, wql, bq, qtmp, m0);
        gemm3<<<gg, 256, 0, stream>>>(xh, xl, wkh, wkl, bk, kout, m0);
        gemm3<<<gg, 256, 0, stream>>>(xh, xl, wvh, wvl, bv, vout, m0);
    }

    attn_mfma<<<dim3(SEQ / 128, BATCH * NUM_HEAD), 512, 0, stream>>>(qtmp, kout, vout, attn);

    resid_ln<<<MTOT, 256, 0, stream>>>(x, attn, gamma, beta, out);
}

// Round 7
// 448.224 us; speedup vs baseline: 4.3616x; 1.0542x over previous
//
#include <hip/hip_runtime.h>
#include <math.h>

#define D_MODEL 1024
#define NUM_HEAD 16
#define D_HEAD   64
#define BATCH    4
#define SEQ      2048
#define MTOT     (BATCH*SEQ)   // 8192 rows

typedef __attribute__((ext_vector_type(8))) short short8;
typedef __attribute__((ext_vector_type(4))) short short4v;
typedef __attribute__((ext_vector_type(2))) short short2v;
typedef __attribute__((ext_vector_type(4))) float f32x4;

static __device__ __forceinline__ unsigned short f2bf_u(float f) {
    union { float f; unsigned u; } v; v.f = f;
    return (unsigned short)((v.u + 0x7FFFu + ((v.u >> 16) & 1u)) >> 16);  // RNE
}
static __device__ __forceinline__ short f2bf(float f) { return (short)f2bf_u(f); }
static __device__ __forceinline__ float bf2f(unsigned short h) {
    union { float f; unsigned u; } v; v.u = ((unsigned)h) << 16; return v.f;
}
// v_cvt_pk_bf16_f32: dest.lo = bf16(a), dest.hi = bf16(b)  [T12 primitive]
static __device__ __forceinline__ unsigned cvt_pk_bf16(float a, float b) {
    unsigned r;
    asm volatile("v_cvt_pk_bf16_f32 %0, %1, %2" : "=v"(r) : "v"(a), "v"(b));
    return r;
}

// async 16B global->LDS
#define ASYNC16(ldst, gsrc) __builtin_amdgcn_global_load_lds( \
    (const __attribute__((address_space(1))) unsigned int*)(gsrc), \
    (__attribute__((address_space(3))) unsigned int*)(ldst), 16, 0, 0)

// ---------------------------------------------------------------------------
// conv_x / conv_w / gemm3: split-bf16 GEMM path (unchanged from R4)
// ---------------------------------------------------------------------------
__global__ __launch_bounds__(256) void conv_x(
    const float* __restrict__ x, unsigned short* __restrict__ hi,
    unsigned short* __restrict__ lo, int m0)
{
    const int gid = blockIdx.x * 256 + threadIdx.x;
    const int ml = gid >> 7;
    const int k  = (gid & 127) << 3;
    const float* s = &x[(size_t)(m0 + ml) * D_MODEL + k];
    float4 a = *(const float4*)s;
    float4 b = *(const float4*)(s + 4);
    float vv[8] = {a.x, a.y, a.z, a.w, b.x, b.y, b.z, b.w};
    short8 ph, pl;
#pragma unroll
    for (int j = 0; j < 8; ++j) {
        unsigned short h = f2bf_u(vv[j]);
        ph[j] = (short)h;
        pl[j] = (short)f2bf_u(vv[j] - bf2f(h));
    }
    size_t off = ((size_t)(ml >> 7) * 32 + (k >> 5)) * 4096
               + (size_t)(ml & 127) * 32 + (k & 31);
    *(short8*)&hi[off] = ph;
    *(short8*)&lo[off] = pl;
}

__global__ __launch_bounds__(256) void conv_w(
    const float* __restrict__ W, unsigned short* __restrict__ hi,
    unsigned short* __restrict__ lo)
{
    __shared__ float Tr[32][132];
    const int t  = threadIdx.x;
    const int n0 = blockIdx.x * 128, k0 = blockIdx.y * 32;
#pragma unroll
    for (int it = 0; it < 4; ++it) {
        int idx = it * 256 + t;
        int kr = idx >> 5, c = (idx & 31) * 4;
        *(float4*)&Tr[kr][c] = *(const float4*)&W[(size_t)(k0 + kr) * D_MODEL + n0 + c];
    }
    __syncthreads();
    const int n = t >> 1, kh = (t & 1) * 16;
    short8 ph0, ph1, pl0, pl1;
#pragma unroll
    for (int j = 0; j < 16; ++j) {
        float v = Tr[kh + j][n];
        unsigned short h = f2bf_u(v);
        unsigned short lw = f2bf_u(v - bf2f(h));
        if (j < 8) { ph0[j] = (short)h; pl0[j] = (short)lw; }
        else       { ph1[j - 8] = (short)h; pl1[j - 8] = (short)lw; }
    }
    size_t base = ((size_t)blockIdx.x * 32 + blockIdx.y) * 4096 + (size_t)n * 32 + kh;
    *(short8*)&hi[base]     = ph0;
    *(short8*)&hi[base + 8] = ph1;
    *(short8*)&lo[base]     = pl0;
    *(short8*)&lo[base + 8] = pl1;
}

__global__ __launch_bounds__(256) void gemm3(
    const unsigned short* __restrict__ Ah, const unsigned short* __restrict__ Al,
    const unsigned short* __restrict__ Bh, const unsigned short* __restrict__ Bl,
    const float* __restrict__ bias, float* __restrict__ Y, int m0)
{
    __shared__ unsigned short lds[16384];
    unsigned short* LA  = lds;
    unsigned short* LB  = lds + 4096;
    unsigned short* LAl = lds + 8192;
    unsigned short* LBl = lds + 12288;

    const int t  = threadIdx.x;
    const int l  = t & 63, w = t >> 6;
    const int lq = l & 15, g = l >> 4;
    const int wr = w >> 1, wc = w & 1;

    const size_t abase = (size_t)blockIdx.y * 32 * 4096;
    const size_t bbase = (size_t)blockIdx.x * 32 * 4096;

    f32x4 acc[4][4];
#pragma unroll
    for (int i = 0; i < 4; ++i)
#pragma unroll
        for (int j = 0; j < 4; ++j) { acc[i][j][0]=0.f; acc[i][j][1]=0.f; acc[i][j][2]=0.f; acc[i][j][3]=0.f; }

    for (int ks = 0; ks < 32; ++ks) {
        const unsigned short* ga  = Ah + abase + (size_t)ks * 4096;
        const unsigned short* gal = Al + abase + (size_t)ks * 4096;
        const unsigned short* gb  = Bh + bbase + (size_t)ks * 4096;
        const unsigned short* gbl = Bl + bbase + (size_t)ks * 4096;
        __syncthreads();
        ASYNC16(&LA [t*8],        ga  + t*8);
        ASYNC16(&LA [2048 + t*8], ga  + 2048 + t*8);
        ASYNC16(&LB [t*8],        gb  + t*8);
        ASYNC16(&LB [2048 + t*8], gb  + 2048 + t*8);
        ASYNC16(&LAl[t*8],        gal + t*8);
        ASYNC16(&LAl[2048 + t*8], gal + 2048 + t*8);
        ASYNC16(&LBl[t*8],        gbl + t*8);
        ASYNC16(&LBl[2048 + t*8], gbl + 2048 + t*8);
        __syncthreads();

        short8 ah[4], al[4];
#pragma unroll
        for (int fm = 0; fm < 4; ++fm) {
            int off = (wr*64 + fm*16 + lq) * 32 + g*8;
            ah[fm] = *(const short8*)&LA [off];
            al[fm] = *(const short8*)&LAl[off];
        }
#pragma unroll
        for (int fn = 0; fn < 4; ++fn) {
            int off = (wc*64 + fn*16 + lq) * 32 + g*8;
            short8 bh = *(const short8*)&LB [off];
            short8 bl = *(const short8*)&LBl[off];
#pragma unroll
            for (int fm = 0; fm < 4; ++fm) {
                acc[fm][fn] = __builtin_amdgcn_mfma_f32_16x16x32_bf16(ah[fm], bh, acc[fm][fn], 0, 0, 0);
                acc[fm][fn] = __builtin_amdgcn_mfma_f32_16x16x32_bf16(al[fm], bh, acc[fm][fn], 0, 0, 0);
                acc[fm][fn] = __builtin_amdgcn_mfma_f32_16x16x32_bf16(ah[fm], bl, acc[fm][fn], 0, 0, 0);
            }
        }
    }

    const int nb = blockIdx.x*128 + wc*64;
#pragma unroll
    for (int fn = 0; fn < 4; ++fn) {
        int n = nb + fn*16 + lq;
        int h = n >> 6, dl = n & 63;
        float bv = bias[n];
#pragma unroll
        for (int fm = 0; fm < 4; ++fm) {
            int mg = m0 + blockIdx.y*128 + wr*64 + fm*16 + g*4;
#pragma unroll
            for (int r = 0; r < 4; ++r) {
                int m  = mg + r;
                int bi = m >> 11, sr = m & (SEQ - 1);
                Y[(((size_t)bi*NUM_HEAD + h)*SEQ + sr)*D_HEAD + dl] = acc[fm][fn][r] + bv;
            }
        }
    }
}

// ---------------------------------------------------------------------------
// pack_kv: fp32 K,V (B,H,S,dh) -> bf16 K (same layout) + bf16 V^T (B,H,dh,S).
// One block per (bh, 64-row s-tile). V transposed via padded LDS.
// ---------------------------------------------------------------------------
__global__ __launch_bounds__(256) void pack_kv(
    const float* __restrict__ Kf, const float* __restrict__ Vf,
    unsigned short* __restrict__ Kb, unsigned short* __restrict__ VTb)
{
    __shared__ float vt[64][65];
    const int bh = blockIdx.y;
    const int s0 = blockIdx.x * 64;
    const int t  = threadIdx.x;
    const int r  = t >> 2;             // 0..63
    const int c  = (t & 3) * 16;       // 0,16,32,48

    // --- K: straight convert, coalesced ---
    {
        const float* ks = Kf + ((size_t)bh*SEQ + s0 + r) * D_HEAD + c;
        float4 f0 = ((const float4*)ks)[0], f1 = ((const float4*)ks)[1];
        float4 f2 = ((const float4*)ks)[2], f3 = ((const float4*)ks)[3];
        float v0[8] = {f0.x,f0.y,f0.z,f0.w,f1.x,f1.y,f1.z,f1.w};
        float v1[8] = {f2.x,f2.y,f2.z,f2.w,f3.x,f3.y,f3.z,f3.w};
        short8 o0, o1;
#pragma unroll
        for (int j = 0; j < 8; ++j) { o0[j] = f2bf(v0[j]); o1[j] = f2bf(v1[j]); }
        unsigned short* kd = Kb + ((size_t)bh*SEQ + s0 + r) * D_HEAD + c;
        *(short8*)kd = o0; *(short8*)(kd + 8) = o1;
    }

    // --- V: load tile to LDS, transpose, convert, write V^T ---
    {
        const float* vs = Vf + ((size_t)bh*SEQ + s0 + r) * D_HEAD + c;
        float4 f0 = ((const float4*)vs)[0], f1 = ((const float4*)vs)[1];
        float4 f2 = ((const float4*)vs)[2], f3 = ((const float4*)vs)[3];
        float vv[16] = {f0.x,f0.y,f0.z,f0.w,f1.x,f1.y,f1.z,f1.w,
                        f2.x,f2.y,f2.z,f2.w,f3.x,f3.y,f3.z,f3.w};
#pragma unroll
        for (int j = 0; j < 16; ++j) vt[r][c + j] = vv[j];
    }
    __syncthreads();
    {
        const int d  = t >> 2;           // 0..63 (V^T row)
        const int kv = (t & 3) * 16;     // kv chunk
        short8 o0, o1;
#pragma unroll
        for (int j = 0; j < 8; ++j)  o0[j] = f2bf(vt[kv + j][d]);
#pragma unroll
        for (int j = 0; j < 8; ++j)  o1[j] = f2bf(vt[kv + 8 + j][d]);
        unsigned short* vd = VTb + ((size_t)bh*D_HEAD + d) * SEQ + s0 + kv;
        *(short8*)vd = o0; *(short8*)(vd + 8) = o1;
    }
}

// ---------------------------------------------------------------------------
// attn_mfma2: causal flash attention; bf16 K / V^T consumed directly via
// async global_load_lds (pre-swizzled per-lane SOURCE, linear LDS dest,
// swizzled reads). Double-buffered staging with counted vmcnt (T3/T4-lite).
// LDS: K dbuf 2x8K [0,16K) | VT dbuf 2x8K [16K,32K) | P per-wave [32K,48K)
// ---------------------------------------------------------------------------
__global__ __launch_bounds__(512) void attn_mfma2(
    const float* __restrict__ Q, const unsigned short* __restrict__ Kbf,
    const unsigned short* __restrict__ VT, float* __restrict__ O)
{
    __shared__ __attribute__((aligned(16))) char smem[48*1024];
    const int t  = threadIdx.x;
    const int w  = t >> 6;
    const int l  = t & 63;
    const int lq = l & 15;
    const int g  = l >> 4;

    const int bh = blockIdx.y;
    const int q0 = blockIdx.x * 128;
    const float* Qb = Q + (size_t)bh * SEQ * D_HEAD;
    const char*  Kb = (const char*)(Kbf + (size_t)bh * SEQ * D_HEAD);   // [S][128B]
    const char*  Vb = (const char*)(VT  + (size_t)bh * D_HEAD * SEQ);   // [64][S*2B]

    const int qrow = q0 + w*16 + lq;

    // Q fragment via cvt_pk: lane holds Q[qrow][32c + g*8 + j]/8
    short8 qf[2];
    {
        const float* qp = &Qb[(size_t)qrow * D_HEAD];
#pragma unroll
        for (int c = 0; c < 2; ++c) {
            float4 x0 = *(const float4*)&qp[c*32 + g*8];
            float4 x1 = *(const float4*)&qp[c*32 + g*8 + 4];
            union { unsigned u[4]; short8 s8; } pk;
            pk.u[0] = cvt_pk_bf16(x0.x*0.125f, x0.y*0.125f);
            pk.u[1] = cvt_pk_bf16(x0.z*0.125f, x0.w*0.125f);
            pk.u[2] = cvt_pk_bf16(x1.x*0.125f, x1.y*0.125f);
            pk.u[3] = cvt_pk_bf16(x1.z*0.125f, x1.w*0.125f);
            qf[c] = pk.s8;
        }
    }

    f32x4 o[4];
#pragma unroll
    for (int i = 0; i < 4; ++i) { o[i][0]=0.f; o[i][1]=0.f; o[i][2]=0.f; o[i][3]=0.f; }
    float m = -INFINITY, lsum = 0.f;

    const int pbase = 32768 + w*2048;

    // staging geometry: thread t stages 16B; LDS dest linear t*16 within tile;
    // source byte pre-swizzled so swizzled reads see row-major data.
    const int srow  = t >> 3;                                  // 0..63
    const int sbyte = ((t & 7) * 16) ^ ((srow & 7) << 4);      // involution
    const int ldst  = t * 16;

#define STAGE(bufi, kv0) do {                                                   \
    ASYNC16(smem + (bufi)*8192 + ldst,                                          \
            Kb + (size_t)((kv0) + srow) * 128 + sbyte);                         \
    ASYNC16(smem + 16384 + (bufi)*8192 + ldst,                                  \
            Vb + (size_t)srow * (SEQ*2) + (size_t)(kv0) * 2 + sbyte);           \
} while (0)

    const int nt = (q0 >> 6) + 2;   // kv tiles of 64: 0 .. q0+64
    STAGE(0, 0);

    for (int ti = 0; ti < nt; ++ti) {
        const int cur = ti & 1;
        const int kvb = ti * 64;
        if (ti + 1 < nt) {
            STAGE(cur ^ 1, kvb + 64);
            asm volatile("s_waitcnt vmcnt(2)" ::: "memory");
        } else {
            asm volatile("s_waitcnt vmcnt(0)" ::: "memory");
        }
        __builtin_amdgcn_s_barrier();
        __builtin_amdgcn_sched_barrier(0);

        const char* kbase = smem + cur*8192;
        const char* vbase = smem + 16384 + cur*8192;

        // --- S^T = K · Q^T ---
        f32x4 st[4];
        __builtin_amdgcn_s_setprio(1);
#pragma unroll
        for (int tt = 0; tt < 4; ++tt) {
            int row = tt*16 + lq;
            const char* base = kbase + row*128;
            short8 ka0 = *(const short8*)(base + ((     16*g) ^ ((row & 7) << 4)));
            short8 ka1 = *(const short8*)(base + ((64 + 16*g) ^ ((row & 7) << 4)));
            f32x4 z; z[0]=0.f; z[1]=0.f; z[2]=0.f; z[3]=0.f;
            z = __builtin_amdgcn_mfma_f32_16x16x32_bf16(ka0, qf[0], z, 0, 0, 0);
            z = __builtin_amdgcn_mfma_f32_16x16x32_bf16(ka1, qf[1], z, 0, 0, 0);
            st[tt] = z;
        }
        __builtin_amdgcn_s_setprio(0);

        // --- mask + online softmax (q = lq; kv = kvb + 16tt + 4g + r) ---
        float tmax = -INFINITY;
#pragma unroll
        for (int tt = 0; tt < 4; ++tt)
#pragma unroll
            for (int r = 0; r < 4; ++r) {
                int kv = kvb + tt*16 + g*4 + r;
                float s = (kv <= qrow) ? st[tt][r] : -INFINITY;
                st[tt][r] = s;
                tmax = fmaxf(tmax, s);
            }
        tmax = fmaxf(tmax, __shfl_xor(tmax, 16));
        tmax = fmaxf(tmax, __shfl_xor(tmax, 32));

        float mnew = fmaxf(m, tmax);
        float scl  = __expf(m - mnew);
        m = mnew;
        lsum *= scl;
        float sr0 = __shfl(scl, 20*g + 0);
        float sr1 = __shfl(scl, 20*g + 1);
        float sr2 = __shfl(scl, 20*g + 2);
        float sr3 = __shfl(scl, 20*g + 3);
#pragma unroll
        for (int dc = 0; dc < 4; ++dc) {
            o[dc][0] *= sr0; o[dc][1] *= sr1; o[dc][2] *= sr2; o[dc][3] *= sr3;
        }

        // --- P = exp(S^T - m): cvt_pk pack to wave-private LDS ---
#pragma unroll
        for (int tt = 0; tt < 4; ++tt) {
            float p0 = __expf(st[tt][0] - mnew);
            float p1 = __expf(st[tt][1] - mnew);
            float p2f= __expf(st[tt][2] - mnew);
            float p3 = __expf(st[tt][3] - mnew);
            lsum += (p0 + p1) + (p2f + p3);
            uint2 pw;
            pw.x = cvt_pk_bf16(p0, p1);
            pw.y = cvt_pk_bf16(p2f, p3);
            *(uint2*)(smem + pbase + lq*128 + ((32*tt + 8*g) ^ ((lq & 7) << 4))) = pw;
        }

        // --- O += P · V ---
        short8 pa0 = *(const short8*)(smem + pbase + lq*128 + ((     16*g) ^ ((lq & 7) << 4)));
        short8 pa1 = *(const short8*)(smem + pbase + lq*128 + ((64 + 16*g) ^ ((lq & 7) << 4)));
        __builtin_amdgcn_s_setprio(1);
#pragma unroll
        for (int dc = 0; dc < 4; ++dc) {
            int row = dc*16 + lq;
            const char* vb = vbase + row*128;
            short8 v0 = *(const short8*)(vb + ((     16*g) ^ ((row & 7) << 4)));
            short8 v1 = *(const short8*)(vb + ((64 + 16*g) ^ ((row & 7) << 4)));
            o[dc] = __builtin_amdgcn_mfma_f32_16x16x32_bf16(pa0, v0, o[dc], 0, 0, 0);
            o[dc] = __builtin_amdgcn_mfma_f32_16x16x32_bf16(pa1, v1, o[dc], 0, 0, 0);
        }
        __builtin_amdgcn_s_setprio(0);

        __builtin_amdgcn_sched_barrier(0);
        __builtin_amdgcn_s_barrier();
    }
#undef STAGE

    lsum += __shfl_xor(lsum, 16);
    lsum += __shfl_xor(lsum, 32);
    float linv = 1.f / lsum;
    float lr0 = __shfl(linv, 20*g + 0);
    float lr1 = __shfl(linv, 20*g + 1);
    float lr2 = __shfl(linv, 20*g + 2);
    float lr3 = __shfl(linv, 20*g + 3);

    const int b = bh >> 4, h = bh & 15;
    float* Ob = O + ((size_t)b * SEQ + q0 + w*16) * D_MODEL + h * D_HEAD;
#pragma unroll
    for (int dc = 0; dc < 4; ++dc) {
        int col = dc*16 + lq;
        Ob[(4*g + 0)*D_MODEL + col] = o[dc][0] * lr0;
        Ob[(4*g + 1)*D_MODEL + col] = o[dc][1] * lr1;
        Ob[(4*g + 2)*D_MODEL + col] = o[dc][2] * lr2;
        Ob[(4*g + 3)*D_MODEL + col] = o[dc][3] * lr3;
    }
}

// ---------------------------------------------------------------------------
// attn_mfma (R4 version) — fallback when ws_size < 64 MiB
// ---------------------------------------------------------------------------
__global__ __launch_bounds__(512) void attn_mfma(
    const float* __restrict__ Q, const float* __restrict__ K,
    const float* __restrict__ V, float* __restrict__ O)
{
    __shared__ char smem[32*1024];
    const int t  = threadIdx.x;
    const int w  = t >> 6;
    const int l  = t & 63;
    const int lq = l & 15;
    const int g  = l >> 4;

    const int bh = blockIdx.y;
    const int q0 = blockIdx.x * 128;
    const float* Qb = Q + (size_t)bh * SEQ * D_HEAD;
    const float* Kb = K + (size_t)bh * SEQ * D_HEAD;
    const float* Vb = V + (size_t)bh * SEQ * D_HEAD;

    const int qrow = q0 + w*16 + lq;

    short8 qf[2];
    {
        const float* qp = &Qb[(size_t)qrow * D_HEAD];
#pragma unroll
        for (int c = 0; c < 2; ++c) {
            float4 x0 = *(const float4*)&qp[c*32 + g*8];
            float4 x1 = *(const float4*)&qp[c*32 + g*8 + 4];
            short8 f;
            f[0]=f2bf(x0.x*0.125f); f[1]=f2bf(x0.y*0.125f);
            f[2]=f2bf(x0.z*0.125f); f[3]=f2bf(x0.w*0.125f);
            f[4]=f2bf(x1.x*0.125f); f[5]=f2bf(x1.y*0.125f);
            f[6]=f2bf(x1.z*0.125f); f[7]=f2bf(x1.w*0.125f);
            qf[c] = f;
        }
    }

    f32x4 o[4];
#pragma unroll
    for (int i = 0; i < 4; ++i) { o[i][0]=0.f; o[i][1]=0.f; o[i][2]=0.f; o[i][3]=0.f; }
    float m = -INFINITY, lsum = 0.f;

    const int pbase = 16384 + w*2048;
    const int dd  = (t & 15) * 4;
    const int rot = (t >> 1) & 3;

    for (int kvb = 0; kvb <= q0 + 64; kvb += 64) {
        __syncthreads();
#pragma unroll
        for (int u = 0; u < 2; ++u) {
            int kv = (t >> 4) + 32*u;
            float4 x = *(const float4*)&Kb[(size_t)(kvb + kv) * D_HEAD + dd];
            short4v pk; pk[0]=f2bf(x.x); pk[1]=f2bf(x.y); pk[2]=f2bf(x.z); pk[3]=f2bf(x.w);
            *(short4v*)(smem + kv*128 + ((dd*2) ^ ((kv & 7) << 4))) = pk;
        }
        {
            int p2 = t >> 4;
            float4 a = *(const float4*)&Vb[(size_t)(kvb + 2*p2    ) * D_HEAD + dd];
            float4 b = *(const float4*)&Vb[(size_t)(kvb + 2*p2 + 1) * D_HEAD + dd];
            float av[4] = {a.x, a.y, a.z, a.w};
            float bv[4] = {b.x, b.y, b.z, b.w};
#pragma unroll
            for (int j = 0; j < 4; ++j) {
                int jp  = (j + rot) & 3;
                int row = dd + jp;
                short2v pk; pk[0] = f2bf(av[jp]); pk[1] = f2bf(bv[jp]);
                *(short2v*)(smem + 8192 + row*128 + ((p2*4) ^ ((row & 7) << 4))) = pk;
            }
        }
        __syncthreads();

        f32x4 st[4];
#pragma unroll
        for (int tt = 0; tt < 4; ++tt) {
            int row = tt*16 + lq;
            const char* base = smem + row*128;
            short8 ka0 = *(const short8*)(base + ((     16*g) ^ ((row & 7) << 4)));
            short8 ka1 = *(const short8*)(base + ((64 + 16*g) ^ ((row & 7) << 4)));
            f32x4 z; z[0]=0.f; z[1]=0.f; z[2]=0.f; z[3]=0.f;
            z = __builtin_amdgcn_mfma_f32_16x16x32_bf16(ka0, qf[0], z, 0, 0, 0);
            z = __builtin_amdgcn_mfma_f32_16x16x32_bf16(ka1, qf[1], z, 0, 0, 0);
            st[tt] = z;
        }

        float tmax = -INFINITY;
#pragma unroll
        for (int tt = 0; tt < 4; ++tt)
#pragma unroll
            for (int r = 0; r < 4; ++r) {
                int kv = kvb + tt*16 + g*4 + r;
                float s = (kv <= qrow) ? st[tt][r] : -INFINITY;
                st[tt][r] = s;
                tmax = fmaxf(tmax, s);
            }
        tmax = fmaxf(tmax, __shfl_xor(tmax, 16));
        tmax = fmaxf(tmax, __shfl_xor(tmax, 32));

        float mnew = fmaxf(m, tmax);
        float scl  = __expf(m - mnew);
        m = mnew;
        lsum *= scl;
        float sr0 = __shfl(scl, 20*g + 0);
        float sr1 = __shfl(scl, 20*g + 1);
        float sr2 = __shfl(scl, 20*g + 2);
        float sr3 = __shfl(scl, 20*g + 3);
#pragma unroll
        for (int dc = 0; dc < 4; ++dc) {
            o[dc][0] *= sr0; o[dc][1] *= sr1; o[dc][2] *= sr2; o[dc][3] *= sr3;
        }

#pragma unroll
        for (int tt = 0; tt < 4; ++tt) {
            float p0 = __expf(st[tt][0] - mnew);
            float p1 = __expf(st[tt][1] - mnew);
            float p2f= __expf(st[tt][2] - mnew);
            float p3 = __expf(st[tt][3] - mnew);
            lsum += (p0 + p1) + (p2f + p3);
            short4v pk; pk[0]=f2bf(p0); pk[1]=f2bf(p1); pk[2]=f2bf(p2f); pk[3]=f2bf(p3);
            *(short4v*)(smem + pbase + lq*128 + ((32*tt + 8*g) ^ ((lq & 7) << 4))) = pk;
        }

        short8 pa0 = *(const short8*)(smem + pbase + lq*128 + ((     16*g) ^ ((lq & 7) << 4)));
        short8 pa1 = *(const short8*)(smem + pbase + lq*128 + ((64 + 16*g) ^ ((lq & 7) << 4)));
#pragma unroll
        for (int dc = 0; dc < 4; ++dc) {
            int row = dc*16 + lq;
            const char* vb = smem + 8192 + row*128;
            short8 v0 = *(const short8*)(vb + ((     16*g) ^ ((row & 7) << 4)));
            short8 v1 = *(const short8*)(vb + ((64 + 16*g) ^ ((row & 7) << 4)));
            o[dc] = __builtin_amdgcn_mfma_f32_16x16x32_bf16(pa0, v0, o[dc], 0, 0, 0);
            o[dc] = __builtin_amdgcn_mfma_f32_16x16x32_bf16(pa1, v1, o[dc], 0, 0, 0);
        }
    }

    lsum += __shfl_xor(lsum, 16);
    lsum += __shfl_xor(lsum, 32);
    float linv = 1.f / lsum;
    float lr0 = __shfl(linv, 20*g + 0);
    float lr1 = __shfl(linv, 20*g + 1);
    float lr2 = __shfl(linv, 20*g + 2);
    float lr3 = __shfl(linv, 20*g + 3);

    const int b = bh >> 4, h = bh & 15;
    float* Ob = O + ((size_t)b * SEQ + q0 + w*16) * D_MODEL + h * D_HEAD;
#pragma unroll
    for (int dc = 0; dc < 4; ++dc) {
        int col = dc*16 + lq;
        Ob[(4*g + 0)*D_MODEL + col] = o[dc][0] * lr0;
        Ob[(4*g + 1)*D_MODEL + col] = o[dc][1] * lr1;
        Ob[(4*g + 2)*D_MODEL + col] = o[dc][2] * lr2;
        Ob[(4*g + 3)*D_MODEL + col] = o[dc][3] * lr3;
    }
}

// ---------------------------------------------------------------------------
// resid_ln (unchanged)
// ---------------------------------------------------------------------------
__global__ __launch_bounds__(256) void resid_ln(
    const float* __restrict__ X, const float* __restrict__ A,
    const float* __restrict__ gamma, const float* __restrict__ beta,
    float* __restrict__ Out)
{
    const int rowi = blockIdx.x;
    const size_t base = (size_t)rowi * D_MODEL;
    const int t = threadIdx.x;
    const int c = t * 4;

    float4 xv = *(const float4*)&X[base + c];
    float4 av = *(const float4*)&A[base + c];
    float v0 = xv.x + av.x, v1 = xv.y + av.y, v2 = xv.z + av.z, v3 = xv.w + av.w;

    float s1 = v0 + v1 + v2 + v3;
    float s2 = v0*v0 + v1*v1 + v2*v2 + v3*v3;

#pragma unroll
    for (int off = 32; off > 0; off >>= 1) {
        s1 += __shfl_down(s1, off);
        s2 += __shfl_down(s2, off);
    }

    __shared__ float r1[4], r2[4];
    __shared__ float mu_s, rstd_s;
    const int wid = t >> 6, lane = t & 63;
    if (lane == 0) { r1[wid] = s1; r2[wid] = s2; }
    __syncthreads();
    if (t == 0) {
        float S1 = r1[0]+r1[1]+r1[2]+r1[3];
        float S2 = r2[0]+r2[1]+r2[2]+r2[3];
        float mu  = S1 * (1.f/1024.f);
        float var = S2 * (1.f/1024.f) - mu*mu;
        mu_s   = mu;
        rstd_s = rsqrtf(var + 1e-5f);
    }
    __syncthreads();
    const float mu = mu_s, rstd = rstd_s;

    float4 gq = *(const float4*)&gamma[c];
    float4 be = *(const float4*)&beta[c];
    float4 ov = make_float4((v0-mu)*rstd*gq.x + be.x,
                            (v1-mu)*rstd*gq.y + be.y,
                            (v2-mu)*rstd*gq.z + be.z,
                            (v3-mu)*rstd*gq.w + be.w);
    *(float4*)&Out[base + c] = ov;
}

// ---------------------------------------------------------------------------
extern "C" void kernel_launch(void* const* d_in, const int* in_sizes, int n_in,
                              void* d_out, int out_size, void* d_ws, size_t ws_size,
                              hipStream_t stream)
{
    (void)in_sizes; (void)n_in; (void)out_size;

    const float* x     = (const float*)d_in[0];
    const float* Wq    = (const float*)d_in[1];
    const float* bq    = (const float*)d_in[2];
    const float* Wk    = (const float*)d_in[3];
    const float* bk    = (const float*)d_in[4];
    const float* Wv    = (const float*)d_in[5];
    const float* bv    = (const float*)d_in[6];
    const float* gamma = (const float*)d_in[7];
    const float* beta  = (const float*)d_in[8];

    float* out  = (float*)d_out;
    float* kout = out  + (size_t)MTOT * D_MODEL;
    float* vout = kout + (size_t)MTOT * D_MODEL;
    float* qtmp = out;             // park q (B,H,S,dh) in out-region; LN overwrites last
    float* attn = (float*)d_ws;    // time-shares pack region (packs dead post-GEMM)

    const size_t MB = 1024*1024;
    const size_t W_ELT = (size_t)D_MODEL * D_MODEL;
    const size_t need_full = (size_t)MTOT*D_MODEL*2*2 + 6*W_ELT*2;   // 46.1 MB
    const bool newpath = (ws_size >= 64*MB);
    const int nh = (newpath || ws_size >= need_full) ? 1 : 2;
    const int HM = MTOT / nh;

    unsigned short* xh  = (unsigned short*)d_ws;
    unsigned short* xl  = xh + (size_t)HM * D_MODEL;
    unsigned short* wp  = xl + (size_t)HM * D_MODEL;
    unsigned short* wqh = wp;             unsigned short* wql = wqh + W_ELT;
    unsigned short* wkh = wql + W_ELT;    unsigned short* wkl = wkh + W_ELT;
    unsigned short* wvh = wkl + W_ELT;    unsigned short* wvl = wvh + W_ELT;

    conv_w<<<dim3(8, 32), 256, 0, stream>>>(Wq, wqh, wql);
    conv_w<<<dim3(8, 32), 256, 0, stream>>>(Wk, wkh, wkl);
    conv_w<<<dim3(8, 32), 256, 0, stream>>>(Wv, wvh, wvl);

    for (int hh = 0; hh < nh; ++hh) {
        const int m0 = hh * HM;
        conv_x<<<HM / 2, 256, 0, stream>>>(x, xh, xl, m0);
        dim3 gg(8, HM / 128);
        gemm3<<<gg, 256, 0, stream>>>(xh, xl, wqh, wql, bq, qtmp, m0);
        gemm3<<<gg, 256, 0, stream>>>(xh, xl, wkh, wkl, bk, kout, m0);
        gemm3<<<gg, 256, 0, stream>>>(xh, xl, wvh, wvl, bv, vout, m0);
    }

    if (newpath) {
        unsigned short* gKbf = (unsigned short*)((char*)d_ws + 32*MB);
        unsigned short* gVT  = (unsigned short*)((char*)d_ws + 48*MB);
        pack_kv<<<dim3(SEQ/64, BATCH*NUM_HEAD), 256, 0, stream>>>(kout, vout, gKbf, gVT);
        attn_mfma2<<<dim3(SEQ/128, BATCH*NUM_HEAD), 512, 0, stream>>>(qtmp, gKbf, gVT, attn);
    } else {
        attn_mfma<<<dim3(SEQ/128, BATCH*NUM_HEAD), 512, 0, stream>>>(qtmp, kout, vout, attn);
    }

    resid_ln<<<MTOT, 256, 0, stream>>>(x, attn, gamma, beta, out);
}

// Round 8
// 422.125 us; speedup vs baseline: 4.6313x; 1.0618x over previous
//
#include <hip/hip_runtime.h>
#include <math.h>

#define D_MODEL 1024
#define NUM_HEAD 16
#define D_HEAD   64
#define BATCH    4
#define SEQ      2048
#define MTOT     (BATCH*SEQ)   // 8192 rows

typedef __attribute__((ext_vector_type(8))) short short8;
typedef __attribute__((ext_vector_type(4))) short short4v;
typedef __attribute__((ext_vector_type(2))) short short2v;
typedef __attribute__((ext_vector_type(4))) float f32x4;

static __device__ __forceinline__ unsigned short f2bf_u(float f) {
    union { float f; unsigned u; } v; v.f = f;
    return (unsigned short)((v.u + 0x7FFFu + ((v.u >> 16) & 1u)) >> 16);  // RNE
}
static __device__ __forceinline__ short f2bf(float f) { return (short)f2bf_u(f); }
static __device__ __forceinline__ float bf2f(unsigned short h) {
    union { float f; unsigned u; } v; v.u = ((unsigned)h) << 16; return v.f;
}
// v_cvt_pk_bf16_f32: dest.lo = bf16(a), dest.hi = bf16(b)  [T12 primitive]
static __device__ __forceinline__ unsigned cvt_pk_bf16(float a, float b) {
    unsigned r;
    asm volatile("v_cvt_pk_bf16_f32 %0, %1, %2" : "=v"(r) : "v"(a), "v"(b));
    return r;
}

// async 16B global->LDS
#define ASYNC16(ldst, gsrc) __builtin_amdgcn_global_load_lds( \
    (const __attribute__((address_space(1))) unsigned int*)(gsrc), \
    (__attribute__((address_space(3))) unsigned int*)(ldst), 16, 0, 0)

// ---------------------------------------------------------------------------
// conv_x: x -> hi/lo bf16 tile packs (unchanged from R4)
// ---------------------------------------------------------------------------
__global__ __launch_bounds__(256) void conv_x(
    const float* __restrict__ x, unsigned short* __restrict__ hi,
    unsigned short* __restrict__ lo, int m0)
{
    const int gid = blockIdx.x * 256 + threadIdx.x;
    const int ml = gid >> 7;
    const int k  = (gid & 127) << 3;
    const float* s = &x[(size_t)(m0 + ml) * D_MODEL + k];
    float4 a = *(const float4*)s;
    float4 b = *(const float4*)(s + 4);
    float vv[8] = {a.x, a.y, a.z, a.w, b.x, b.y, b.z, b.w};
    short8 ph, pl;
#pragma unroll
    for (int j = 0; j < 8; ++j) {
        unsigned short h = f2bf_u(vv[j]);
        ph[j] = (short)h;
        pl[j] = (short)f2bf_u(vv[j] - bf2f(h));
    }
    size_t off = ((size_t)(ml >> 7) * 32 + (k >> 5)) * 4096
               + (size_t)(ml & 127) * 32 + (k & 31);
    *(short8*)&hi[off] = ph;
    *(short8*)&lo[off] = pl;
}

// ---------------------------------------------------------------------------
// conv_w: W -> W^T HI-ONLY bf16 tile pack (2-term split: B-lo term dropped)
// ---------------------------------------------------------------------------
__global__ __launch_bounds__(256) void conv_w(
    const float* __restrict__ W, unsigned short* __restrict__ hi)
{
    __shared__ float Tr[32][132];
    const int t  = threadIdx.x;
    const int n0 = blockIdx.x * 128, k0 = blockIdx.y * 32;
#pragma unroll
    for (int it = 0; it < 4; ++it) {
        int idx = it * 256 + t;
        int kr = idx >> 5, c = (idx & 31) * 4;
        *(float4*)&Tr[kr][c] = *(const float4*)&W[(size_t)(k0 + kr) * D_MODEL + n0 + c];
    }
    __syncthreads();
    const int n = t >> 1, kh = (t & 1) * 16;
    short8 ph0, ph1;
#pragma unroll
    for (int j = 0; j < 16; ++j) {
        unsigned short h = f2bf_u(Tr[kh + j][n]);
        if (j < 8) ph0[j] = (short)h; else ph1[j - 8] = (short)h;
    }
    size_t base = ((size_t)blockIdx.x * 32 + blockIdx.y) * 4096 + (size_t)n * 32 + kh;
    *(short8*)&hi[base]     = ph0;
    *(short8*)&hi[base + 8] = ph1;
}

// ---------------------------------------------------------------------------
// gemm3 (2-term): C = (Ah+Al) @ Bh^T + bias.  32 MFMA/ks (was 48), 24KB LDS.
// ---------------------------------------------------------------------------
__global__ __launch_bounds__(256) void gemm3(
    const unsigned short* __restrict__ Ah, const unsigned short* __restrict__ Al,
    const unsigned short* __restrict__ Bh,
    const float* __restrict__ bias, float* __restrict__ Y, int m0)
{
    __shared__ unsigned short lds[12288];   // 24 KB: Ah | Bh | Al
    unsigned short* LA  = lds;
    unsigned short* LB  = lds + 4096;
    unsigned short* LAl = lds + 8192;

    const int t  = threadIdx.x;
    const int l  = t & 63, w = t >> 6;
    const int lq = l & 15, g = l >> 4;
    const int wr = w >> 1, wc = w & 1;

    const size_t abase = (size_t)blockIdx.y * 32 * 4096;
    const size_t bbase = (size_t)blockIdx.x * 32 * 4096;

    f32x4 acc[4][4];
#pragma unroll
    for (int i = 0; i < 4; ++i)
#pragma unroll
        for (int j = 0; j < 4; ++j) { acc[i][j][0]=0.f; acc[i][j][1]=0.f; acc[i][j][2]=0.f; acc[i][j][3]=0.f; }

    for (int ks = 0; ks < 32; ++ks) {
        const unsigned short* ga  = Ah + abase + (size_t)ks * 4096;
        const unsigned short* gal = Al + abase + (size_t)ks * 4096;
        const unsigned short* gb  = Bh + bbase + (size_t)ks * 4096;
        __syncthreads();
        ASYNC16(&LA [t*8],        ga  + t*8);
        ASYNC16(&LA [2048 + t*8], ga  + 2048 + t*8);
        ASYNC16(&LB [t*8],        gb  + t*8);
        ASYNC16(&LB [2048 + t*8], gb  + 2048 + t*8);
        ASYNC16(&LAl[t*8],        gal + t*8);
        ASYNC16(&LAl[2048 + t*8], gal + 2048 + t*8);
        __syncthreads();

        short8 ah[4], al[4];
#pragma unroll
        for (int fm = 0; fm < 4; ++fm) {
            int off = (wr*64 + fm*16 + lq) * 32 + g*8;
            ah[fm] = *(const short8*)&LA [off];
            al[fm] = *(const short8*)&LAl[off];
        }
#pragma unroll
        for (int fn = 0; fn < 4; ++fn) {
            int off = (wc*64 + fn*16 + lq) * 32 + g*8;
            short8 bh = *(const short8*)&LB[off];
#pragma unroll
            for (int fm = 0; fm < 4; ++fm) {
                acc[fm][fn] = __builtin_amdgcn_mfma_f32_16x16x32_bf16(ah[fm], bh, acc[fm][fn], 0, 0, 0);
                acc[fm][fn] = __builtin_amdgcn_mfma_f32_16x16x32_bf16(al[fm], bh, acc[fm][fn], 0, 0, 0);
            }
        }
    }

    const int nb = blockIdx.x*128 + wc*64;
#pragma unroll
    for (int fn = 0; fn < 4; ++fn) {
        int n = nb + fn*16 + lq;
        int h = n >> 6, dl = n & 63;
        float bv = bias[n];
#pragma unroll
        for (int fm = 0; fm < 4; ++fm) {
            int mg = m0 + blockIdx.y*128 + wr*64 + fm*16 + g*4;
#pragma unroll
            for (int r = 0; r < 4; ++r) {
                int m  = mg + r;
                int bi = m >> 11, sr = m & (SEQ - 1);
                Y[(((size_t)bi*NUM_HEAD + h)*SEQ + sr)*D_HEAD + dl] = acc[fm][fn][r] + bv;
            }
        }
    }
}

// ---------------------------------------------------------------------------
// pack_kv: fp32 K,V (B,H,S,dh) -> bf16 K + bf16 V^T (unchanged from R7)
// ---------------------------------------------------------------------------
__global__ __launch_bounds__(256) void pack_kv(
    const float* __restrict__ Kf, const float* __restrict__ Vf,
    unsigned short* __restrict__ Kb, unsigned short* __restrict__ VTb)
{
    __shared__ float vt[64][65];
    const int bh = blockIdx.y;
    const int s0 = blockIdx.x * 64;
    const int t  = threadIdx.x;
    const int r  = t >> 2;
    const int c  = (t & 3) * 16;

    {
        const float* ks = Kf + ((size_t)bh*SEQ + s0 + r) * D_HEAD + c;
        float4 f0 = ((const float4*)ks)[0], f1 = ((const float4*)ks)[1];
        float4 f2 = ((const float4*)ks)[2], f3 = ((const float4*)ks)[3];
        float v0[8] = {f0.x,f0.y,f0.z,f0.w,f1.x,f1.y,f1.z,f1.w};
        float v1[8] = {f2.x,f2.y,f2.z,f2.w,f3.x,f3.y,f3.z,f3.w};
        short8 o0, o1;
#pragma unroll
        for (int j = 0; j < 8; ++j) { o0[j] = f2bf(v0[j]); o1[j] = f2bf(v1[j]); }
        unsigned short* kd = Kb + ((size_t)bh*SEQ + s0 + r) * D_HEAD + c;
        *(short8*)kd = o0; *(short8*)(kd + 8) = o1;
    }

    {
        const float* vs = Vf + ((size_t)bh*SEQ + s0 + r) * D_HEAD + c;
        float4 f0 = ((const float4*)vs)[0], f1 = ((const float4*)vs)[1];
        float4 f2 = ((const float4*)vs)[2], f3 = ((const float4*)vs)[3];
        float vv[16] = {f0.x,f0.y,f0.z,f0.w,f1.x,f1.y,f1.z,f1.w,
                        f2.x,f2.y,f2.z,f2.w,f3.x,f3.y,f3.z,f3.w};
#pragma unroll
        for (int j = 0; j < 16; ++j) vt[r][c + j] = vv[j];
    }
    __syncthreads();
    {
        const int d  = t >> 2;
        const int kv = (t & 3) * 16;
        short8 o0, o1;
#pragma unroll
        for (int j = 0; j < 8; ++j)  o0[j] = f2bf(vt[kv + j][d]);
#pragma unroll
        for (int j = 0; j < 8; ++j)  o1[j] = f2bf(vt[kv + 8 + j][d]);
        unsigned short* vd = VTb + ((size_t)bh*D_HEAD + d) * SEQ + s0 + kv;
        *(short8*)vd = o0; *(short8*)(vd + 8) = o1;
    }
}

// ---------------------------------------------------------------------------
// attn_mfma2 (R7-proven) + heavy-first q-tile order (causal load balance).
// ---------------------------------------------------------------------------
__global__ __launch_bounds__(512) void attn_mfma2(
    const float* __restrict__ Q, const unsigned short* __restrict__ Kbf,
    const unsigned short* __restrict__ VT, float* __restrict__ O)
{
    __shared__ __attribute__((aligned(16))) char smem[48*1024];
    const int t  = threadIdx.x;
    const int w  = t >> 6;
    const int l  = t & 63;
    const int lq = l & 15;
    const int g  = l >> 4;

    const int bh = blockIdx.y;
    const int q0 = (gridDim.x - 1 - blockIdx.x) * 128;   // heavy-first
    const float* Qb = Q + (size_t)bh * SEQ * D_HEAD;
    const char*  Kb = (const char*)(Kbf + (size_t)bh * SEQ * D_HEAD);   // [S][128B]
    const char*  Vb = (const char*)(VT  + (size_t)bh * D_HEAD * SEQ);   // [64][S*2B]

    const int qrow = q0 + w*16 + lq;

    short8 qf[2];
    {
        const float* qp = &Qb[(size_t)qrow * D_HEAD];
#pragma unroll
        for (int c = 0; c < 2; ++c) {
            float4 x0 = *(const float4*)&qp[c*32 + g*8];
            float4 x1 = *(const float4*)&qp[c*32 + g*8 + 4];
            union { unsigned u[4]; short8 s8; } pk;
            pk.u[0] = cvt_pk_bf16(x0.x*0.125f, x0.y*0.125f);
            pk.u[1] = cvt_pk_bf16(x0.z*0.125f, x0.w*0.125f);
            pk.u[2] = cvt_pk_bf16(x1.x*0.125f, x1.y*0.125f);
            pk.u[3] = cvt_pk_bf16(x1.z*0.125f, x1.w*0.125f);
            qf[c] = pk.s8;
        }
    }

    f32x4 o[4];
#pragma unroll
    for (int i = 0; i < 4; ++i) { o[i][0]=0.f; o[i][1]=0.f; o[i][2]=0.f; o[i][3]=0.f; }
    float m = -INFINITY, lsum = 0.f;

    const int pbase = 32768 + w*2048;

    const int srow  = t >> 3;
    const int sbyte = ((t & 7) * 16) ^ ((srow & 7) << 4);
    const int ldst  = t * 16;

#define STAGE(bufi, kv0) do {                                                   \
    ASYNC16(smem + (bufi)*8192 + ldst,                                          \
            Kb + (size_t)((kv0) + srow) * 128 + sbyte);                         \
    ASYNC16(smem + 16384 + (bufi)*8192 + ldst,                                  \
            Vb + (size_t)srow * (SEQ*2) + (size_t)(kv0) * 2 + sbyte);           \
} while (0)

    const int nt = (q0 >> 6) + 2;
    STAGE(0, 0);

    for (int ti = 0; ti < nt; ++ti) {
        const int cur = ti & 1;
        const int kvb = ti * 64;
        if (ti + 1 < nt) {
            STAGE(cur ^ 1, kvb + 64);
            asm volatile("s_waitcnt vmcnt(2)" ::: "memory");
        } else {
            asm volatile("s_waitcnt vmcnt(0)" ::: "memory");
        }
        __builtin_amdgcn_s_barrier();
        __builtin_amdgcn_sched_barrier(0);

        const char* kbase = smem + cur*8192;
        const char* vbase = smem + 16384 + cur*8192;

        f32x4 st[4];
        __builtin_amdgcn_s_setprio(1);
#pragma unroll
        for (int tt = 0; tt < 4; ++tt) {
            int row = tt*16 + lq;
            const char* base = kbase + row*128;
            short8 ka0 = *(const short8*)(base + ((     16*g) ^ ((row & 7) << 4)));
            short8 ka1 = *(const short8*)(base + ((64 + 16*g) ^ ((row & 7) << 4)));
            f32x4 z; z[0]=0.f; z[1]=0.f; z[2]=0.f; z[3]=0.f;
            z = __builtin_amdgcn_mfma_f32_16x16x32_bf16(ka0, qf[0], z, 0, 0, 0);
            z = __builtin_amdgcn_mfma_f32_16x16x32_bf16(ka1, qf[1], z, 0, 0, 0);
            st[tt] = z;
        }
        __builtin_amdgcn_s_setprio(0);

        float tmax = -INFINITY;
#pragma unroll
        for (int tt = 0; tt < 4; ++tt)
#pragma unroll
            for (int r = 0; r < 4; ++r) {
                int kv = kvb + tt*16 + g*4 + r;
                float s = (kv <= qrow) ? st[tt][r] : -INFINITY;
                st[tt][r] = s;
                tmax = fmaxf(tmax, s);
            }
        tmax = fmaxf(tmax, __shfl_xor(tmax, 16));
        tmax = fmaxf(tmax, __shfl_xor(tmax, 32));

        float mnew = fmaxf(m, tmax);
        float scl  = __expf(m - mnew);
        m = mnew;
        lsum *= scl;
        float sr0 = __shfl(scl, 20*g + 0);
        float sr1 = __shfl(scl, 20*g + 1);
        float sr2 = __shfl(scl, 20*g + 2);
        float sr3 = __shfl(scl, 20*g + 3);
#pragma unroll
        for (int dc = 0; dc < 4; ++dc) {
            o[dc][0] *= sr0; o[dc][1] *= sr1; o[dc][2] *= sr2; o[dc][3] *= sr3;
        }

#pragma unroll
        for (int tt = 0; tt < 4; ++tt) {
            float p0 = __expf(st[tt][0] - mnew);
            float p1 = __expf(st[tt][1] - mnew);
            float p2f= __expf(st[tt][2] - mnew);
            float p3 = __expf(st[tt][3] - mnew);
            lsum += (p0 + p1) + (p2f + p3);
            uint2 pw;
            pw.x = cvt_pk_bf16(p0, p1);
            pw.y = cvt_pk_bf16(p2f, p3);
            *(uint2*)(smem + pbase + lq*128 + ((32*tt + 8*g) ^ ((lq & 7) << 4))) = pw;
        }

        short8 pa0 = *(const short8*)(smem + pbase + lq*128 + ((     16*g) ^ ((lq & 7) << 4)));
        short8 pa1 = *(const short8*)(smem + pbase + lq*128 + ((64 + 16*g) ^ ((lq & 7) << 4)));
        __builtin_amdgcn_s_setprio(1);
#pragma unroll
        for (int dc = 0; dc < 4; ++dc) {
            int row = dc*16 + lq;
            const char* vb = vbase + row*128;
            short8 v0 = *(const short8*)(vb + ((     16*g) ^ ((row & 7) << 4)));
            short8 v1 = *(const short8*)(vb + ((64 + 16*g) ^ ((row & 7) << 4)));
            o[dc] = __builtin_amdgcn_mfma_f32_16x16x32_bf16(pa0, v0, o[dc], 0, 0, 0);
            o[dc] = __builtin_amdgcn_mfma_f32_16x16x32_bf16(pa1, v1, o[dc], 0, 0, 0);
        }
        __builtin_amdgcn_s_setprio(0);

        __builtin_amdgcn_sched_barrier(0);
        __builtin_amdgcn_s_barrier();
    }
#undef STAGE

    lsum += __shfl_xor(lsum, 16);
    lsum += __shfl_xor(lsum, 32);
    float linv = 1.f / lsum;
    float lr0 = __shfl(linv, 20*g + 0);
    float lr1 = __shfl(linv, 20*g + 1);
    float lr2 = __shfl(linv, 20*g + 2);
    float lr3 = __shfl(linv, 20*g + 3);

    const int b = bh >> 4, h = bh & 15;
    float* Ob = O + ((size_t)b * SEQ + q0 + w*16) * D_MODEL + h * D_HEAD;
#pragma unroll
    for (int dc = 0; dc < 4; ++dc) {
        int col = dc*16 + lq;
        Ob[(4*g + 0)*D_MODEL + col] = o[dc][0] * lr0;
        Ob[(4*g + 1)*D_MODEL + col] = o[dc][1] * lr1;
        Ob[(4*g + 2)*D_MODEL + col] = o[dc][2] * lr2;
        Ob[(4*g + 3)*D_MODEL + col] = o[dc][3] * lr3;
    }
}

// ---------------------------------------------------------------------------
// resid_ln (unchanged)
// ---------------------------------------------------------------------------
__global__ __launch_bounds__(256) void resid_ln(
    const float* __restrict__ X, const float* __restrict__ A,
    const float* __restrict__ gamma, const float* __restrict__ beta,
    float* __restrict__ Out)
{
    const int rowi = blockIdx.x;
    const size_t base = (size_t)rowi * D_MODEL;
    const int t = threadIdx.x;
    const int c = t * 4;

    float4 xv = *(const float4*)&X[base + c];
    float4 av = *(const float4*)&A[base + c];
    float v0 = xv.x + av.x, v1 = xv.y + av.y, v2 = xv.z + av.z, v3 = xv.w + av.w;

    float s1 = v0 + v1 + v2 + v3;
    float s2 = v0*v0 + v1*v1 + v2*v2 + v3*v3;

#pragma unroll
    for (int off = 32; off > 0; off >>= 1) {
        s1 += __shfl_down(s1, off);
        s2 += __shfl_down(s2, off);
    }

    __shared__ float r1[4], r2[4];
    __shared__ float mu_s, rstd_s;
    const int wid = t >> 6, lane = t & 63;
    if (lane == 0) { r1[wid] = s1; r2[wid] = s2; }
    __syncthreads();
    if (t == 0) {
        float S1 = r1[0]+r1[1]+r1[2]+r1[3];
        float S2 = r2[0]+r2[1]+r2[2]+r2[3];
        float mu  = S1 * (1.f/1024.f);
        float var = S2 * (1.f/1024.f) - mu*mu;
        mu_s   = mu;
        rstd_s = rsqrtf(var + 1e-5f);
    }
    __syncthreads();
    const float mu = mu_s, rstd = rstd_s;

    float4 gq = *(const float4*)&gamma[c];
    float4 be = *(const float4*)&beta[c];
    float4 ov = make_float4((v0-mu)*rstd*gq.x + be.x,
                            (v1-mu)*rstd*gq.y + be.y,
                            (v2-mu)*rstd*gq.z + be.z,
                            (v3-mu)*rstd*gq.w + be.w);
    *(float4*)&Out[base + c] = ov;
}

// ---------------------------------------------------------------------------
extern "C" void kernel_launch(void* const* d_in, const int* in_sizes, int n_in,
                              void* d_out, int out_size, void* d_ws, size_t ws_size,
                              hipStream_t stream)
{
    (void)in_sizes; (void)n_in; (void)out_size; (void)ws_size;

    const float* x     = (const float*)d_in[0];
    const float* Wq    = (const float*)d_in[1];
    const float* bq    = (const float*)d_in[2];
    const float* Wk    = (const float*)d_in[3];
    const float* bk    = (const float*)d_in[4];
    const float* Wv    = (const float*)d_in[5];
    const float* bv    = (const float*)d_in[6];
    const float* gamma = (const float*)d_in[7];
    const float* beta  = (const float*)d_in[8];

    float* out  = (float*)d_out;
    float* kout = out  + (size_t)MTOT * D_MODEL;
    float* vout = kout + (size_t)MTOT * D_MODEL;
    float* qtmp = out;             // park q (B,H,S,dh) in out-region; LN overwrites last
    float* attn = (float*)d_ws;    // [0,32MiB) — x packs dead post-GEMM

    const size_t MB = 1024*1024;
    const size_t W_ELT = (size_t)D_MODEL * D_MODEL;

    // ws layout (ws >= 64 MiB, proven R7):
    //   [0,16)   xh      [16,32)  xl
    //   [32,38)  W hi packs (q,k,v) — dead before pack_kv
    //   [32,48)  Kbf     [48,64)  VT   (time-share W region post-GEMM)
    unsigned short* xh  = (unsigned short*)d_ws;
    unsigned short* xl  = xh + (size_t)MTOT * D_MODEL;
    unsigned short* wqh = (unsigned short*)((char*)d_ws + 32*MB);
    unsigned short* wkh = wqh + W_ELT;
    unsigned short* wvh = wkh + W_ELT;

    conv_w<<<dim3(8, 32), 256, 0, stream>>>(Wq, wqh);
    conv_w<<<dim3(8, 32), 256, 0, stream>>>(Wk, wkh);
    conv_w<<<dim3(8, 32), 256, 0, stream>>>(Wv, wvh);

    conv_x<<<MTOT / 2, 256, 0, stream>>>(x, xh, xl, 0);
    dim3 gg(8, MTOT / 128);
    gemm3<<<gg, 256, 0, stream>>>(xh, xl, wqh, bq, qtmp, 0);
    gemm3<<<gg, 256, 0, stream>>>(xh, xl, wkh, bk, kout, 0);
    gemm3<<<gg, 256, 0, stream>>>(xh, xl, wvh, bv, vout, 0);

    unsigned short* gKbf = (unsigned short*)((char*)d_ws + 32*MB);
    unsigned short* gVT  = (unsigned short*)((char*)d_ws + 48*MB);
    pack_kv<<<dim3(SEQ/64, BATCH*NUM_HEAD), 256, 0, stream>>>(kout, vout, gKbf, gVT);
    attn_mfma2<<<dim3(SEQ/128, BATCH*NUM_HEAD), 512, 0, stream>>>(qtmp, gKbf, gVT, attn);

    resid_ln<<<MTOT, 256, 0, stream>>>(x, attn, gamma, beta, out);
}